// Round 10
// baseline (315.065 us; speedup 1.0000x reference)
//
#include <hip/hip_runtime.h>

#define NFEAT 128
#define RS 256   // combined-plane row stride in shorts: [0,128)=H, [128,256)=L

using bf16x8 = __attribute__((ext_vector_type(8))) short;
using f32x4  = __attribute__((ext_vector_type(4))) float;

__device__ __forceinline__ float bf2f(unsigned short u) {
    union { unsigned int i; float f; } v; v.i = ((unsigned int)u) << 16; return v.f;
}
__device__ __forceinline__ float bfhi2f(unsigned int hi16) {
    union { unsigned int i; float f; } v; v.i = hi16; return v.f;
}
__device__ __forceinline__ unsigned short f2bf(float f) {      // RNE
    union { float f; unsigned int i; } v; v.f = f;
    unsigned int i = v.i;
    return (unsigned short)((i + 0x7FFFu + ((i >> 16) & 1u)) >> 16);
}

// ---------------- CSR build (XCD-sliced hist/fill) ----------------

__global__ void hist_kernel(const int* __restrict__ dst, int* __restrict__ cnt,
                            int nE, int sliceN) {
    const int slice = blockIdx.x & 7;
    const int lo = slice * sliceN, hi = lo + sliceN;
    const int nb = gridDim.x >> 3;
    const int bs = blockIdx.x >> 3;
    for (int i = bs * 256 + threadIdx.x; i < nE; i += nb * 256) {
        int d = dst[i];
        if (d >= lo && d < hi) atomicAdd(&cnt[d], 1);
    }
}

__global__ void fill_kernel(const int* __restrict__ src, const int* __restrict__ dst,
                            int* __restrict__ cnt, int* __restrict__ col_idx,
                            int nE, int sliceN) {
    const int slice = blockIdx.x & 7;
    const int lo = slice * sliceN, hi = lo + sliceN;
    const int nb = gridDim.x >> 3;
    const int bs = blockIdx.x >> 3;
    for (int i = bs * 256 + threadIdx.x; i < nE; i += nb * 256) {
        int d = dst[i];
        int s = src[i];
        if (d >= lo && d < hi) {
            int pos = atomicAdd(&cnt[d], 1);
            col_idx[pos] = s;
        }
    }
}

__global__ void blocksum_kernel(const int* __restrict__ cnt, int* __restrict__ blockSum, int n) {
    int i = blockIdx.x * 256 + threadIdx.x;
    int d = (i < n) ? cnt[i] : 0;
    int lane = threadIdx.x & 63, wid = threadIdx.x >> 6;
    __shared__ int ws[4];
    int v = d;
    for (int off = 32; off; off >>= 1) v += __shfl_down(v, off);
    if (lane == 0) ws[wid] = v;
    __syncthreads();
    if (threadIdx.x == 0) blockSum[blockIdx.x] = ws[0] + ws[1] + ws[2] + ws[3];
}

__global__ void scan_write_kernel(int* __restrict__ cnt, const int* __restrict__ blockSum,
                                  int* __restrict__ row_ptr, float* __restrict__ inv_deg,
                                  int n) {
    const int b = blockIdx.x, tid = threadIdx.x;
    const int lane = tid & 63, wid = tid >> 6;
    __shared__ int wsA[4];
    __shared__ int wsB[4];
    int v = (tid < b) ? blockSum[tid] : 0;
    for (int off = 32; off; off >>= 1) v += __shfl_down(v, off);
    if (lane == 0) wsA[wid] = v;
    int i = b * 256 + tid;
    int d = (i < n) ? cnt[i] : 0;
    int s = d;
    for (int off = 1; off < 64; off <<= 1) {
        int t = __shfl_up(s, off);
        if (lane >= off) s += t;
    }
    if (lane == 63) wsB[wid] = s;
    __syncthreads();
    int blockOff = wsA[0] + wsA[1] + wsA[2] + wsA[3];
    int wOff = 0;
    for (int w = 0; w < wid; ++w) wOff += wsB[w];
    int excl = blockOff + wOff + s - d;
    if (i < n) {
        row_ptr[i] = excl;
        cnt[i]     = excl;
        inv_deg[i] = 1.0f / (float)(d > 1 ? d : 1);
    }
    if (i == n) row_ptr[n] = excl;
}

// ---------------- conversions ----------------

__global__ void xconv_kernel(const float* __restrict__ x, unsigned short* __restrict__ xc, int n) {
    int i = blockIdx.x * 256 + threadIdx.x;
    if (i >= n * 32) return;
    int node = i >> 5, fb = (i & 31) * 4;
    float4 v = *(const float4*)(x + (size_t)node * NFEAT + fb);
    unsigned short h0 = f2bf(v.x), h1 = f2bf(v.y), h2 = f2bf(v.z), h3 = f2bf(v.w);
    uint2 hw;
    hw.x = (unsigned int)h0 | ((unsigned int)h1 << 16);
    hw.y = (unsigned int)h2 | ((unsigned int)h3 << 16);
    *(uint2*)(xc + (size_t)node * RS + fb) = hw;
    unsigned short l0 = f2bf(v.x - bf2f(h0)), l1 = f2bf(v.y - bf2f(h1));
    unsigned short l2 = f2bf(v.z - bf2f(h2)), l3 = f2bf(v.w - bf2f(h3));
    uint2 lw;
    lw.x = (unsigned int)l0 | ((unsigned int)l1 << 16);
    lw.y = (unsigned int)l2 | ((unsigned int)l3 << 16);
    *(uint2*)(xc + (size_t)node * RS + 128 + fb) = lw;
}

// W -> transposed K-major cat [nout][256], H plane only, PRE-SWIZZLED:
// element (c,k) stored at c*256 + (k ^ ((c&7)<<3)).
__global__ void wconv_kernel(const float* __restrict__ Wl, const float* __restrict__ Wr,
                             unsigned short* __restrict__ Wsz, int nout) {
    int idx = blockIdx.x * 256 + threadIdx.x;
    if (idx >= nout * 256) return;
    int c = idx >> 8, k = idx & 255;
    float f = (k < 128) ? Wl[k * nout + c] : Wr[(k - 128) * nout + c];
    Wsz[c * 256 + (k ^ ((c & 7) << 3))] = f2bf(f);
}

// ---------------- mean aggregation (CSR gather, H-plane, uint4) ----------------
__global__ void agg_kernel(const unsigned short* __restrict__ in,
                           const int* __restrict__ row_ptr, const int* __restrict__ col_idx,
                           const float* __restrict__ inv_deg,
                           unsigned short* __restrict__ agg, int n) {
    int lane = threadIdx.x & 15;
    int node = blockIdx.x * 16 + (threadIdx.x >> 4);
    if (node >= n) return;
    int beg = row_ptr[node], end = row_ptr[node + 1];
    float a[4][8];
    #pragma unroll
    for (int u = 0; u < 4; ++u)
        #pragma unroll
        for (int j = 0; j < 8; ++j) a[u][j] = 0.f;
    auto acc8 = [&](float* A, uint4 v) {
        A[0] += bfhi2f(v.x << 16); A[1] += bfhi2f(v.x & 0xFFFF0000u);
        A[2] += bfhi2f(v.y << 16); A[3] += bfhi2f(v.y & 0xFFFF0000u);
        A[4] += bfhi2f(v.z << 16); A[5] += bfhi2f(v.z & 0xFFFF0000u);
        A[6] += bfhi2f(v.w << 16); A[7] += bfhi2f(v.w & 0xFFFF0000u);
    };
    int e = beg;
    for (; e + 8 <= end; e += 8) {
        uint4 v[8];
        #pragma unroll
        for (int u = 0; u < 8; ++u) {
            int s = col_idx[e + u];
            v[u] = *(const uint4*)(in + (size_t)s * RS + lane * 8);
        }
        #pragma unroll
        for (int u = 0; u < 8; ++u) acc8(a[u & 3], v[u]);
    }
    for (; e < end; ++e) {
        int s = col_idx[e];
        uint4 v = *(const uint4*)(in + (size_t)s * RS + lane * 8);
        acc8(a[0], v);
    }
    float sc = inv_deg[node];
    unsigned short hs[8], ls[8];
    #pragma unroll
    for (int j = 0; j < 8; ++j) {
        float m = ((a[0][j] + a[1][j]) + (a[2][j] + a[3][j])) * sc;
        hs[j] = f2bf(m);
        ls[j] = f2bf(m - bf2f(hs[j]));
    }
    uint4 hv, lv;
    hv.x = (unsigned int)hs[0] | ((unsigned int)hs[1] << 16);
    hv.y = (unsigned int)hs[2] | ((unsigned int)hs[3] << 16);
    hv.z = (unsigned int)hs[4] | ((unsigned int)hs[5] << 16);
    hv.w = (unsigned int)hs[6] | ((unsigned int)hs[7] << 16);
    lv.x = (unsigned int)ls[0] | ((unsigned int)ls[1] << 16);
    lv.y = (unsigned int)ls[2] | ((unsigned int)ls[3] << 16);
    lv.z = (unsigned int)ls[4] | ((unsigned int)ls[5] << 16);
    lv.w = (unsigned int)ls[6] | ((unsigned int)ls[7] << 16);
    *(uint4*)(agg + (size_t)node * RS + lane * 8)       = hv;
    *(uint4*)(agg + (size_t)node * RS + 128 + lane * 8) = lv;
}

// ---------------- MFMA GEMM: C = [agg|x] @ W_hi + b, split-A bf16 ----------------
// Round-10 structure: ONE latency wait per block.
//   - W tile (64 cols x 256 k, swizzled) staged via global_load_lds (16B,
//     wave-uniform base + lane*16 -- the staging copy is exactly lane-linear).
//   - ALL A fragments (2 rows x 2 planes x 8 ksteps = 128 VGPR) issued before
//     the barrier; used-once loads -> RA cannot rematerialize (rounds 5-7
//     lesson); sched_barrier(0) pins issue order; the barrier's vmcnt drain is
//     the single wait, A latency hides under W staging.
//   - 1D grid, XCD-paired: blocks (x,y=0/1) differ by nx8 (multiple of 8) ->
//     same XCD -> col-tiles share A rows in L2 (round-9: FETCH doubled).

template<int NOUT, bool RELU, bool FINAL>
__global__ __launch_bounds__(256, 2) void mfma_gemm(
    const unsigned short* __restrict__ aggc, const unsigned short* __restrict__ xc,
    const unsigned short* __restrict__ Wsz, const float* __restrict__ bias,
    float* __restrict__ outF, unsigned short* __restrict__ outC, int n, int nx8)
{
    __shared__ char smem[32768];
    const int tid  = threadIdx.x;
    const int wid  = tid >> 6, lane = tid & 63;
    const int wc   = wid & 1,  wr   = wid >> 1;
    const int bx   = blockIdx.x % nx8;
    const int by   = blockIdx.x / nx8;
    if (bx * 64 >= n) return;
    const int colTile = by * 64;

    // stage W tile via global_load_lds: per wave, 8 chunks of 1KB (lane*16)
    {
        const char* wsrc = (const char*)(Wsz + (size_t)colTile * 256);
        #pragma unroll
        for (int i = 0; i < 8; ++i) {
            const int off = i * 4096 + wid * 1024;
            __builtin_amdgcn_global_load_lds(
                (const __attribute__((address_space(1))) unsigned int*)(wsrc + off + lane * 16),
                (__attribute__((address_space(3))) unsigned int*)(smem + off),
                16, 0, 0);
        }
    }

    const int lrow = lane & 15;
    const int lk   = (lane >> 4) * 8;
    const int lkb  = (lane >> 4) * 16;

    const int rowBase = bx * 64 + wr * 32;
    int r0 = rowBase + lrow;      if (r0 > n - 1) r0 = n - 1;
    int r1 = rowBase + 16 + lrow; if (r1 > n - 1) r1 = n - 1;

    const unsigned short* Ar0 = aggc + (size_t)r0 * RS;
    const unsigned short* Ar1 = aggc + (size_t)r1 * RS;
    const unsigned short* Xr0 = xc   + (size_t)r0 * RS;
    const unsigned short* Xr1 = xc   + (size_t)r1 * RS;

    // full-depth A prefetch: 32 x bf16x8 = 128 VGPR, all issued before barrier
    bf16x8 aA0h[4], aA0l[4], aA1h[4], aA1l[4];
    bf16x8 aX0h[4], aX0l[4], aX1h[4], aX1l[4];
    #pragma unroll
    for (int ks = 0; ks < 4; ++ks) {
        const int kk = ks * 32 + lk;
        aA0h[ks] = *(const bf16x8*)(Ar0 + kk);
        aA0l[ks] = *(const bf16x8*)(Ar0 + 128 + kk);
        aA1h[ks] = *(const bf16x8*)(Ar1 + kk);
        aA1l[ks] = *(const bf16x8*)(Ar1 + 128 + kk);
        aX0h[ks] = *(const bf16x8*)(Xr0 + kk);
        aX0l[ks] = *(const bf16x8*)(Xr0 + 128 + kk);
        aX1h[ks] = *(const bf16x8*)(Xr1 + kk);
        aX1l[ks] = *(const bf16x8*)(Xr1 + 128 + kk);
    }
    __builtin_amdgcn_sched_barrier(0);   // pin: all loads issued before the wait
    __syncthreads();                     // single vmcnt drain (W in LDS, A in regs)

    int cbase[2], xmask[2];
    #pragma unroll
    for (int nf = 0; nf < 2; ++nf) {
        int cc = wc * 32 + nf * 16 + lrow;
        cbase[nf] = (cc << 9) + lkb;
        xmask[nf] = (cc & 7) << 4;
    }

    f32x4 acc[2][2];
    #pragma unroll
    for (int mf = 0; mf < 2; ++mf)
        #pragma unroll
        for (int nf = 0; nf < 2; ++nf)
            acc[mf][nf] = (f32x4){0.f, 0.f, 0.f, 0.f};

    bf16x8 b0 = *(const bf16x8*)(smem + (cbase[0] ^ xmask[0]));
    bf16x8 b1 = *(const bf16x8*)(smem + (cbase[1] ^ xmask[1]));

    #pragma unroll
    for (int ks = 0; ks < 8; ++ks) {
        bf16x8 d0 = b0, d1 = b1;
        if (ks < 7) {
            const int ksn = ks + 1;
            b0 = *(const bf16x8*)(smem + ((cbase[0] + (ksn << 6)) ^ xmask[0]));
            b1 = *(const bf16x8*)(smem + ((cbase[1] + (ksn << 6)) ^ xmask[1]));
        }
        const bf16x8 c0h = (ks < 4) ? aA0h[ks & 3] : aX0h[ks & 3];
        const bf16x8 c0l = (ks < 4) ? aA0l[ks & 3] : aX0l[ks & 3];
        const bf16x8 c1h = (ks < 4) ? aA1h[ks & 3] : aX1h[ks & 3];
        const bf16x8 c1l = (ks < 4) ? aA1l[ks & 3] : aX1l[ks & 3];
        acc[0][0] = __builtin_amdgcn_mfma_f32_16x16x32_bf16(c0h, d0, acc[0][0], 0, 0, 0);
        acc[0][0] = __builtin_amdgcn_mfma_f32_16x16x32_bf16(c0l, d0, acc[0][0], 0, 0, 0);
        acc[1][0] = __builtin_amdgcn_mfma_f32_16x16x32_bf16(c1h, d0, acc[1][0], 0, 0, 0);
        acc[1][0] = __builtin_amdgcn_mfma_f32_16x16x32_bf16(c1l, d0, acc[1][0], 0, 0, 0);
        acc[0][1] = __builtin_amdgcn_mfma_f32_16x16x32_bf16(c0h, d1, acc[0][1], 0, 0, 0);
        acc[0][1] = __builtin_amdgcn_mfma_f32_16x16x32_bf16(c0l, d1, acc[0][1], 0, 0, 0);
        acc[1][1] = __builtin_amdgcn_mfma_f32_16x16x32_bf16(c1h, d1, acc[1][1], 0, 0, 0);
        acc[1][1] = __builtin_amdgcn_mfma_f32_16x16x32_bf16(c1l, d1, acc[1][1], 0, 0, 0);
    }

    #pragma unroll
    for (int mf = 0; mf < 2; ++mf) {
        #pragma unroll
        for (int nf = 0; nf < 2; ++nf) {
            const int c = colTile + wc * 32 + nf * 16 + lrow;
            const float bv = bias[c];
            #pragma unroll
            for (int reg = 0; reg < 4; ++reg) {
                const int r = rowBase + mf * 16 + (lane >> 4) * 4 + reg;
                if (r < n) {
                    float h = acc[mf][nf][reg] + bv;
                    if (RELU) h = fmaxf(h, 0.f);
                    if (FINAL) {
                        outF[(size_t)r * NOUT + c] = h;
                    } else {
                        unsigned short hi = f2bf(h);
                        outC[(size_t)r * RS + c]       = hi;
                        outC[(size_t)r * RS + 128 + c] = f2bf(h - bf2f(hi));
                    }
                }
            }
        }
    }
}

extern "C" void kernel_launch(void* const* d_in, const int* in_sizes, int n_in,
                              void* d_out, int out_size, void* d_ws, size_t ws_size,
                              hipStream_t stream) {
    const float* x   = (const float*)d_in[0];
    const int*   ei  = (const int*)d_in[1];
    const float* Wl0 = (const float*)d_in[2];
    const float* Wr0 = (const float*)d_in[3];
    const float* b0  = (const float*)d_in[4];
    const float* Wl1 = (const float*)d_in[5];
    const float* Wr1 = (const float*)d_in[6];
    const float* b1  = (const float*)d_in[7];
    const float* Wl2 = (const float*)d_in[8];
    const float* Wr2 = (const float*)d_in[9];
    const float* b2  = (const float*)d_in[10];

    const int nN = in_sizes[0] / NFEAT;       // 50000
    const int nE = in_sizes[1] / 2;           // 800000
    const int* src = ei;
    const int* dst = ei + nE;

    char* ws = (char*)d_ws;
    size_t off = 0;
    auto take = [&](size_t bytes) { char* p = ws + off; off += (bytes + 255) & ~(size_t)255; return p; };
    int*   cnt      = (int*)  take((size_t)nN * 4);
    int*   row_ptr  = (int*)  take((size_t)(nN + 1) * 4);
    int*   col_idx  = (int*)  take((size_t)nE * 4);
    float* inv_deg  = (float*)take((size_t)nN * 4);
    int*   blockSum = (int*)  take(256 * 4);
    const size_t plane = (size_t)nN * RS * 2;
    unsigned short* aggC = (unsigned short*)take(plane);
    unsigned short* xc0  = (unsigned short*)take(plane);
    unsigned short* xc1  = (unsigned short*)take(plane);
    unsigned short* Wsz0 = (unsigned short*)take(128 * 256 * 2);
    unsigned short* Wsz1 = (unsigned short*)take(128 * 256 * 2);
    unsigned short* Wsz2 = (unsigned short*)take(64 * 256 * 2);
    (void)ws_size; (void)n_in; (void)out_size;

    const int scanBlocks = (nN + 255) / 256;
    const int sliceN = (nN + 7) / 8;

    // CSR build (XCD-sliced hist/fill)
    hipMemsetAsync(cnt, 0, (size_t)nN * 4, stream);
    hist_kernel<<<2048, 256, 0, stream>>>(dst, cnt, nE, sliceN);
    blocksum_kernel<<<scanBlocks, 256, 0, stream>>>(cnt, blockSum, nN);
    scan_write_kernel<<<scanBlocks, 256, 0, stream>>>(cnt, blockSum, row_ptr, inv_deg, nN);
    fill_kernel<<<2048, 256, 0, stream>>>(src, dst, cnt, col_idx, nE, sliceN);

    // conversions
    xconv_kernel<<<(nN * 32 + 255) / 256, 256, 0, stream>>>(x, xc0, nN);
    wconv_kernel<<<(128 * 256 + 255) / 256, 256, 0, stream>>>(Wl0, Wr0, Wsz0, 128);
    wconv_kernel<<<(128 * 256 + 255) / 256, 256, 0, stream>>>(Wl1, Wr1, Wsz1, 128);
    wconv_kernel<<<(64 * 256 + 255) / 256, 256, 0, stream>>>(Wl2, Wr2, Wsz2, 64);

    const int aggGrid = (nN + 15) / 16;
    const int nx  = (nN + 63) / 64;           // 782 row tiles
    const int nx8 = ((nx + 7) / 8) * 8;       // 784 (XCD-paired stride)
    const int gBig = nx8 * 2;                 // NOUT=128: two col tiles, paired per XCD
    const int gFin = nx;                      // NOUT=64: one col tile

    // layer 0: x -> h0
    agg_kernel<<<aggGrid, 256, 0, stream>>>(xc0, row_ptr, col_idx, inv_deg, aggC, nN);
    mfma_gemm<128, true, false><<<gBig, 256, 0, stream>>>(
        aggC, xc0, Wsz0, b0, nullptr, xc1, nN, nx8);
    // layer 1: h0 -> h1
    agg_kernel<<<aggGrid, 256, 0, stream>>>(xc1, row_ptr, col_idx, inv_deg, aggC, nN);
    mfma_gemm<128, true, false><<<gBig, 256, 0, stream>>>(
        aggC, xc1, Wsz1, b1, nullptr, xc0, nN, nx8);
    // layer 2: h1 -> out (fp32)
    agg_kernel<<<aggGrid, 256, 0, stream>>>(xc0, row_ptr, col_idx, inv_deg, aggC, nN);
    mfma_gemm<64, false, true><<<gFin, 256, 0, stream>>>(
        aggC, xc0, Wsz2, b2, (float*)d_out, nullptr, nN, nx);
}

// Round 11
// 291.327 us; speedup vs baseline: 1.0815x; 1.0815x over previous
//
#include <hip/hip_runtime.h>

#define NFEAT 128
#define RS 256   // combined-plane row stride in shorts: [0,128)=H, [128,256)=L

using bf16x8 = __attribute__((ext_vector_type(8))) short;
using f32x4  = __attribute__((ext_vector_type(4))) float;

__device__ __forceinline__ float bf2f(unsigned short u) {
    union { unsigned int i; float f; } v; v.i = ((unsigned int)u) << 16; return v.f;
}
__device__ __forceinline__ float bfhi2f(unsigned int hi16) {
    union { unsigned int i; float f; } v; v.i = hi16; return v.f;
}
__device__ __forceinline__ unsigned short f2bf(float f) {      // RNE
    union { float f; unsigned int i; } v; v.f = f;
    unsigned int i = v.i;
    return (unsigned short)((i + 0x7FFFu + ((i >> 16) & 1u)) >> 16);
}

// ---------------- CSR build (XCD-sliced hist/fill) ----------------

__global__ void hist_kernel(const int* __restrict__ dst, int* __restrict__ cnt,
                            int nE, int sliceN) {
    const int slice = blockIdx.x & 7;
    const int lo = slice * sliceN, hi = lo + sliceN;
    const int nb = gridDim.x >> 3;
    const int bs = blockIdx.x >> 3;
    for (int i = bs * 256 + threadIdx.x; i < nE; i += nb * 256) {
        int d = dst[i];
        if (d >= lo && d < hi) atomicAdd(&cnt[d], 1);
    }
}

__global__ void fill_kernel(const int* __restrict__ src, const int* __restrict__ dst,
                            int* __restrict__ cnt, int* __restrict__ col_idx,
                            int nE, int sliceN) {
    const int slice = blockIdx.x & 7;
    const int lo = slice * sliceN, hi = lo + sliceN;
    const int nb = gridDim.x >> 3;
    const int bs = blockIdx.x >> 3;
    for (int i = bs * 256 + threadIdx.x; i < nE; i += nb * 256) {
        int d = dst[i];
        int s = src[i];
        if (d >= lo && d < hi) {
            int pos = atomicAdd(&cnt[d], 1);
            col_idx[pos] = s;
        }
    }
}

__global__ void blocksum_kernel(const int* __restrict__ cnt, int* __restrict__ blockSum, int n) {
    int i = blockIdx.x * 256 + threadIdx.x;
    int d = (i < n) ? cnt[i] : 0;
    int lane = threadIdx.x & 63, wid = threadIdx.x >> 6;
    __shared__ int ws[4];
    int v = d;
    for (int off = 32; off; off >>= 1) v += __shfl_down(v, off);
    if (lane == 0) ws[wid] = v;
    __syncthreads();
    if (threadIdx.x == 0) blockSum[blockIdx.x] = ws[0] + ws[1] + ws[2] + ws[3];
}

__global__ void scan_write_kernel(int* __restrict__ cnt, const int* __restrict__ blockSum,
                                  int* __restrict__ row_ptr, float* __restrict__ inv_deg,
                                  int n) {
    const int b = blockIdx.x, tid = threadIdx.x;
    const int lane = tid & 63, wid = tid >> 6;
    __shared__ int wsA[4];
    __shared__ int wsB[4];
    int v = (tid < b) ? blockSum[tid] : 0;
    for (int off = 32; off; off >>= 1) v += __shfl_down(v, off);
    if (lane == 0) wsA[wid] = v;
    int i = b * 256 + tid;
    int d = (i < n) ? cnt[i] : 0;
    int s = d;
    for (int off = 1; off < 64; off <<= 1) {
        int t = __shfl_up(s, off);
        if (lane >= off) s += t;
    }
    if (lane == 63) wsB[wid] = s;
    __syncthreads();
    int blockOff = wsA[0] + wsA[1] + wsA[2] + wsA[3];
    int wOff = 0;
    for (int w = 0; w < wid; ++w) wOff += wsB[w];
    int excl = blockOff + wOff + s - d;
    if (i < n) {
        row_ptr[i] = excl;
        cnt[i]     = excl;
        inv_deg[i] = 1.0f / (float)(d > 1 ? d : 1);
    }
    if (i == n) row_ptr[n] = excl;
}

// ---------------- conversions ----------------

__global__ void xconv_kernel(const float* __restrict__ x, unsigned short* __restrict__ xc, int n) {
    int i = blockIdx.x * 256 + threadIdx.x;
    if (i >= n * 32) return;
    int node = i >> 5, fb = (i & 31) * 4;
    float4 v = *(const float4*)(x + (size_t)node * NFEAT + fb);
    unsigned short h0 = f2bf(v.x), h1 = f2bf(v.y), h2 = f2bf(v.z), h3 = f2bf(v.w);
    uint2 hw;
    hw.x = (unsigned int)h0 | ((unsigned int)h1 << 16);
    hw.y = (unsigned int)h2 | ((unsigned int)h3 << 16);
    *(uint2*)(xc + (size_t)node * RS + fb) = hw;
    unsigned short l0 = f2bf(v.x - bf2f(h0)), l1 = f2bf(v.y - bf2f(h1));
    unsigned short l2 = f2bf(v.z - bf2f(h2)), l3 = f2bf(v.w - bf2f(h3));
    uint2 lw;
    lw.x = (unsigned int)l0 | ((unsigned int)l1 << 16);
    lw.y = (unsigned int)l2 | ((unsigned int)l3 << 16);
    *(uint2*)(xc + (size_t)node * RS + 128 + fb) = lw;
}

// W -> transposed K-major cat [nout][256], H plane only, PRE-SWIZZLED:
// element (c,k) stored at c*256 + (k ^ ((c&7)<<3)).
__global__ void wconv_kernel(const float* __restrict__ Wl, const float* __restrict__ Wr,
                             unsigned short* __restrict__ Wsz, int nout) {
    int idx = blockIdx.x * 256 + threadIdx.x;
    if (idx >= nout * 256) return;
    int c = idx >> 8, k = idx & 255;
    float f = (k < 128) ? Wl[k * nout + c] : Wr[(k - 128) * nout + c];
    Wsz[c * 256 + (k ^ ((c & 7) << 3))] = f2bf(f);
}

// ---------------- mean aggregation (CSR gather, H-plane, uint4) ----------------
__global__ void agg_kernel(const unsigned short* __restrict__ in,
                           const int* __restrict__ row_ptr, const int* __restrict__ col_idx,
                           const float* __restrict__ inv_deg,
                           unsigned short* __restrict__ agg, int n) {
    int lane = threadIdx.x & 15;
    int node = blockIdx.x * 16 + (threadIdx.x >> 4);
    if (node >= n) return;
    int beg = row_ptr[node], end = row_ptr[node + 1];
    float a[4][8];
    #pragma unroll
    for (int u = 0; u < 4; ++u)
        #pragma unroll
        for (int j = 0; j < 8; ++j) a[u][j] = 0.f;
    auto acc8 = [&](float* A, uint4 v) {
        A[0] += bfhi2f(v.x << 16); A[1] += bfhi2f(v.x & 0xFFFF0000u);
        A[2] += bfhi2f(v.y << 16); A[3] += bfhi2f(v.y & 0xFFFF0000u);
        A[4] += bfhi2f(v.z << 16); A[5] += bfhi2f(v.z & 0xFFFF0000u);
        A[6] += bfhi2f(v.w << 16); A[7] += bfhi2f(v.w & 0xFFFF0000u);
    };
    int e = beg;
    for (; e + 8 <= end; e += 8) {
        uint4 v[8];
        #pragma unroll
        for (int u = 0; u < 8; ++u) {
            int s = col_idx[e + u];
            v[u] = *(const uint4*)(in + (size_t)s * RS + lane * 8);
        }
        #pragma unroll
        for (int u = 0; u < 8; ++u) acc8(a[u & 3], v[u]);
    }
    for (; e < end; ++e) {
        int s = col_idx[e];
        uint4 v = *(const uint4*)(in + (size_t)s * RS + lane * 8);
        acc8(a[0], v);
    }
    float sc = inv_deg[node];
    unsigned short hs[8], ls[8];
    #pragma unroll
    for (int j = 0; j < 8; ++j) {
        float m = ((a[0][j] + a[1][j]) + (a[2][j] + a[3][j])) * sc;
        hs[j] = f2bf(m);
        ls[j] = f2bf(m - bf2f(hs[j]));
    }
    uint4 hv, lv;
    hv.x = (unsigned int)hs[0] | ((unsigned int)hs[1] << 16);
    hv.y = (unsigned int)hs[2] | ((unsigned int)hs[3] << 16);
    hv.z = (unsigned int)hs[4] | ((unsigned int)hs[5] << 16);
    hv.w = (unsigned int)hs[6] | ((unsigned int)hs[7] << 16);
    lv.x = (unsigned int)ls[0] | ((unsigned int)ls[1] << 16);
    lv.y = (unsigned int)ls[2] | ((unsigned int)ls[3] << 16);
    lv.z = (unsigned int)ls[4] | ((unsigned int)ls[5] << 16);
    lv.w = (unsigned int)ls[6] | ((unsigned int)ls[7] << 16);
    *(uint4*)(agg + (size_t)node * RS + lane * 8)       = hv;
    *(uint4*)(agg + (size_t)node * RS + 128 + lane * 8) = lv;
}

// ---------------- MFMA GEMM: C = [agg|x] @ W_hi + b, split-A bf16 ----------------
// Round-11 structure (round-10 lesson: the single vmcnt(0) drain + burst pattern
// left the memory system idle; FETCH is already at the ideal minimum, so the
// ONLY lever is continuous pipelining):
//   - ONE __syncthreads total (W staging via global_load_lds, overlapped with
//     the first A prefetches). The K-loop is BARRIER-FREE: W is read-only in
//     LDS, each wave owns its rows -> compiler emits counted vmcnt waits.
//   - Wave = 32 rows x 64 cols (4 B-frags): MFMA/wave doubles to 128 while
//     A-load count stays 32 -> better issue:MFMA ratio.
//   - A depth-2 kstep prefetch (8 loads / 32 VGPR in flight -- small enough
//     that RA has never collapsed this size).

template<int NOUT, bool RELU, bool FINAL>
__global__ __launch_bounds__(256, 3) void mfma_gemm(
    const unsigned short* __restrict__ aggc, const unsigned short* __restrict__ xc,
    const unsigned short* __restrict__ Wsz, const float* __restrict__ bias,
    float* __restrict__ outF, unsigned short* __restrict__ outC, int n, int nRowTiles)
{
    __shared__ char smem[32768];
    const int tid  = threadIdx.x;
    const int wid  = tid >> 6, lane = tid & 63;
    const int rowTileI = blockIdx.x % nRowTiles;
    const int colTile  = (blockIdx.x / nRowTiles) * 64;

    // stage W tile (64 cols x 256 k, pre-swizzled) via global_load_lds
    {
        const char* wsrc = (const char*)(Wsz + (size_t)colTile * 256);
        #pragma unroll
        for (int i = 0; i < 8; ++i) {
            const int off = i * 4096 + wid * 1024;
            __builtin_amdgcn_global_load_lds(
                (const __attribute__((address_space(1))) unsigned int*)(wsrc + off + lane * 16),
                (__attribute__((address_space(3))) unsigned int*)(smem + off),
                16, 0, 0);
        }
    }

    const int lrow = lane & 15;
    const int lk   = (lane >> 4) * 8;
    const int lkb  = (lane >> 4) * 16;

    const int rowBase = rowTileI * 128 + wid * 32;
    int r0 = rowBase + lrow;      if (r0 > n - 1) r0 = n - 1;
    int r1 = rowBase + 16 + lrow; if (r1 > n - 1) r1 = n - 1;

    const unsigned short* Ar0 = aggc + (size_t)r0 * RS;
    const unsigned short* Ar1 = aggc + (size_t)r1 * RS;
    const unsigned short* Xr0 = xc   + (size_t)r0 * RS;
    const unsigned short* Xr1 = xc   + (size_t)r1 * RS;

    // depth-2 A prefetch pipeline (slot = ks & 1)
    bf16x8 p0h[2], p0l[2], p1h[2], p1l[2];
    auto loadA = [&](int ks, int slot) {
        const unsigned short* P0 = (ks < 4) ? Ar0 : Xr0;
        const unsigned short* P1 = (ks < 4) ? Ar1 : Xr1;
        const int kk = (ks & 3) * 32 + lk;
        p0h[slot] = *(const bf16x8*)(P0 + kk);
        p0l[slot] = *(const bf16x8*)(P0 + 128 + kk);
        p1h[slot] = *(const bf16x8*)(P1 + kk);
        p1l[slot] = *(const bf16x8*)(P1 + 128 + kk);
    };
    loadA(0, 0);
    loadA(1, 1);

    // B-frag LDS addressing: byte = (cc*512 + ks*64 + lkb) ^ ((cc&7)<<4)
    int cbase[4], xmask[4];
    #pragma unroll
    for (int nf = 0; nf < 4; ++nf) {
        int cc = nf * 16 + lrow;
        cbase[nf] = (cc << 9) + lkb;
        xmask[nf] = (cc & 7) << 4;
    }

    __syncthreads();            // the ONLY barrier: W in LDS (A ks0/ks1 drain with it)

    f32x4 acc[2][4];
    #pragma unroll
    for (int mf = 0; mf < 2; ++mf)
        #pragma unroll
        for (int nf = 0; nf < 4; ++nf)
            acc[mf][nf] = (f32x4){0.f, 0.f, 0.f, 0.f};

    bf16x8 b0 = *(const bf16x8*)(smem + (cbase[0] ^ xmask[0]));
    bf16x8 b1 = *(const bf16x8*)(smem + (cbase[1] ^ xmask[1]));
    bf16x8 b2 = *(const bf16x8*)(smem + (cbase[2] ^ xmask[2]));
    bf16x8 b3 = *(const bf16x8*)(smem + (cbase[3] ^ xmask[3]));

    #pragma unroll
    for (int ks = 0; ks < 8; ++ks) {
        const int slot = ks & 1;
        const bf16x8 c0h = p0h[slot], c0l = p0l[slot];
        const bf16x8 c1h = p1h[slot], c1l = p1l[slot];
        const bf16x8 d0 = b0, d1 = b1, d2 = b2, d3 = b3;
        if (ks < 6) loadA(ks + 2, slot);           // issue next-next A loads
        if (ks < 7) {                              // issue next B ds_reads
            const int ko = (ks + 1) << 6;
            b0 = *(const bf16x8*)(smem + ((cbase[0] + ko) ^ xmask[0]));
            b1 = *(const bf16x8*)(smem + ((cbase[1] + ko) ^ xmask[1]));
            b2 = *(const bf16x8*)(smem + ((cbase[2] + ko) ^ xmask[2]));
            b3 = *(const bf16x8*)(smem + ((cbase[3] + ko) ^ xmask[3]));
        }
        acc[0][0] = __builtin_amdgcn_mfma_f32_16x16x32_bf16(c0h, d0, acc[0][0], 0, 0, 0);
        acc[0][0] = __builtin_amdgcn_mfma_f32_16x16x32_bf16(c0l, d0, acc[0][0], 0, 0, 0);
        acc[1][0] = __builtin_amdgcn_mfma_f32_16x16x32_bf16(c1h, d0, acc[1][0], 0, 0, 0);
        acc[1][0] = __builtin_amdgcn_mfma_f32_16x16x32_bf16(c1l, d0, acc[1][0], 0, 0, 0);
        acc[0][1] = __builtin_amdgcn_mfma_f32_16x16x32_bf16(c0h, d1, acc[0][1], 0, 0, 0);
        acc[0][1] = __builtin_amdgcn_mfma_f32_16x16x32_bf16(c0l, d1, acc[0][1], 0, 0, 0);
        acc[1][1] = __builtin_amdgcn_mfma_f32_16x16x32_bf16(c1h, d1, acc[1][1], 0, 0, 0);
        acc[1][1] = __builtin_amdgcn_mfma_f32_16x16x32_bf16(c1l, d1, acc[1][1], 0, 0, 0);
        acc[0][2] = __builtin_amdgcn_mfma_f32_16x16x32_bf16(c0h, d2, acc[0][2], 0, 0, 0);
        acc[0][2] = __builtin_amdgcn_mfma_f32_16x16x32_bf16(c0l, d2, acc[0][2], 0, 0, 0);
        acc[1][2] = __builtin_amdgcn_mfma_f32_16x16x32_bf16(c1h, d2, acc[1][2], 0, 0, 0);
        acc[1][2] = __builtin_amdgcn_mfma_f32_16x16x32_bf16(c1l, d2, acc[1][2], 0, 0, 0);
        acc[0][3] = __builtin_amdgcn_mfma_f32_16x16x32_bf16(c0h, d3, acc[0][3], 0, 0, 0);
        acc[0][3] = __builtin_amdgcn_mfma_f32_16x16x32_bf16(c0l, d3, acc[0][3], 0, 0, 0);
        acc[1][3] = __builtin_amdgcn_mfma_f32_16x16x32_bf16(c1h, d3, acc[1][3], 0, 0, 0);
        acc[1][3] = __builtin_amdgcn_mfma_f32_16x16x32_bf16(c1l, d3, acc[1][3], 0, 0, 0);
    }

    // epilogue: bias (+ReLU); FINAL -> fp32 out, else -> combined H|L plane
    #pragma unroll
    for (int mf = 0; mf < 2; ++mf) {
        #pragma unroll
        for (int nf = 0; nf < 4; ++nf) {
            const int c = colTile + nf * 16 + lrow;
            const float bv = bias[c];
            #pragma unroll
            for (int reg = 0; reg < 4; ++reg) {
                const int r = rowBase + mf * 16 + (lane >> 4) * 4 + reg;
                if (r < n) {
                    float h = acc[mf][nf][reg] + bv;
                    if (RELU) h = fmaxf(h, 0.f);
                    if (FINAL) {
                        outF[(size_t)r * NOUT + c] = h;
                    } else {
                        unsigned short hi = f2bf(h);
                        outC[(size_t)r * RS + c]       = hi;
                        outC[(size_t)r * RS + 128 + c] = f2bf(h - bf2f(hi));
                    }
                }
            }
        }
    }
}

extern "C" void kernel_launch(void* const* d_in, const int* in_sizes, int n_in,
                              void* d_out, int out_size, void* d_ws, size_t ws_size,
                              hipStream_t stream) {
    const float* x   = (const float*)d_in[0];
    const int*   ei  = (const int*)d_in[1];
    const float* Wl0 = (const float*)d_in[2];
    const float* Wr0 = (const float*)d_in[3];
    const float* b0  = (const float*)d_in[4];
    const float* Wl1 = (const float*)d_in[5];
    const float* Wr1 = (const float*)d_in[6];
    const float* b1  = (const float*)d_in[7];
    const float* Wl2 = (const float*)d_in[8];
    const float* Wr2 = (const float*)d_in[9];
    const float* b2  = (const float*)d_in[10];

    const int nN = in_sizes[0] / NFEAT;       // 50000
    const int nE = in_sizes[1] / 2;           // 800000
    const int* src = ei;
    const int* dst = ei + nE;

    char* ws = (char*)d_ws;
    size_t off = 0;
    auto take = [&](size_t bytes) { char* p = ws + off; off += (bytes + 255) & ~(size_t)255; return p; };
    int*   cnt      = (int*)  take((size_t)nN * 4);
    int*   row_ptr  = (int*)  take((size_t)(nN + 1) * 4);
    int*   col_idx  = (int*)  take((size_t)nE * 4);
    float* inv_deg  = (float*)take((size_t)nN * 4);
    int*   blockSum = (int*)  take(256 * 4);
    const size_t plane = (size_t)nN * RS * 2;
    unsigned short* aggC = (unsigned short*)take(plane);
    unsigned short* xc0  = (unsigned short*)take(plane);
    unsigned short* xc1  = (unsigned short*)take(plane);
    unsigned short* Wsz0 = (unsigned short*)take(128 * 256 * 2);
    unsigned short* Wsz1 = (unsigned short*)take(128 * 256 * 2);
    unsigned short* Wsz2 = (unsigned short*)take(64 * 256 * 2);
    (void)ws_size; (void)n_in; (void)out_size;

    const int scanBlocks = (nN + 255) / 256;
    const int sliceN = (nN + 7) / 8;

    // CSR build (XCD-sliced hist/fill)
    hipMemsetAsync(cnt, 0, (size_t)nN * 4, stream);
    hist_kernel<<<2048, 256, 0, stream>>>(dst, cnt, nE, sliceN);
    blocksum_kernel<<<scanBlocks, 256, 0, stream>>>(cnt, blockSum, nN);
    scan_write_kernel<<<scanBlocks, 256, 0, stream>>>(cnt, blockSum, row_ptr, inv_deg, nN);
    fill_kernel<<<2048, 256, 0, stream>>>(src, dst, cnt, col_idx, nE, sliceN);

    // conversions
    xconv_kernel<<<(nN * 32 + 255) / 256, 256, 0, stream>>>(x, xc0, nN);
    wconv_kernel<<<(128 * 256 + 255) / 256, 256, 0, stream>>>(Wl0, Wr0, Wsz0, 128);
    wconv_kernel<<<(128 * 256 + 255) / 256, 256, 0, stream>>>(Wl1, Wr1, Wsz1, 128);
    wconv_kernel<<<(64 * 256 + 255) / 256, 256, 0, stream>>>(Wl2, Wr2, Wsz2, 64);

    const int aggGrid   = (nN + 15) / 16;
    const int nRowTiles = (nN + 127) / 128;   // 391 (128 rows per block)
    const int gBig = nRowTiles * 2;           // NOUT=128: two 64-col tiles
    const int gFin = nRowTiles;               // NOUT=64: one col tile

    // layer 0: x -> h0
    agg_kernel<<<aggGrid, 256, 0, stream>>>(xc0, row_ptr, col_idx, inv_deg, aggC, nN);
    mfma_gemm<128, true, false><<<gBig, 256, 0, stream>>>(
        aggC, xc0, Wsz0, b0, nullptr, xc1, nN, nRowTiles);
    // layer 1: h0 -> h1
    agg_kernel<<<aggGrid, 256, 0, stream>>>(xc1, row_ptr, col_idx, inv_deg, aggC, nN);
    mfma_gemm<128, true, false><<<gBig, 256, 0, stream>>>(
        aggC, xc1, Wsz1, b1, nullptr, xc0, nN, nRowTiles);
    // layer 2: h1 -> out (fp32)
    agg_kernel<<<aggGrid, 256, 0, stream>>>(xc0, row_ptr, col_idx, inv_deg, aggC, nN);
    mfma_gemm<64, false, true><<<gFin, 256, 0, stream>>>(
        aggC, xc0, Wsz2, b2, (float*)d_out, nullptr, nN, nRowTiles);
}

// Round 12
// 251.640 us; speedup vs baseline: 1.2520x; 1.1577x over previous
//
#include <hip/hip_runtime.h>

#define NFEAT 128
#define RS 128   // bf16 H-plane row stride in shorts (round-12: L plane dropped)

using bf16x8 = __attribute__((ext_vector_type(8))) short;
using f32x4  = __attribute__((ext_vector_type(4))) float;

__device__ __forceinline__ float bf2f(unsigned short u) {
    union { unsigned int i; float f; } v; v.i = ((unsigned int)u) << 16; return v.f;
}
__device__ __forceinline__ float bfhi2f(unsigned int hi16) {
    union { unsigned int i; float f; } v; v.i = hi16; return v.f;
}
__device__ __forceinline__ unsigned short f2bf(float f) {      // RNE
    union { float f; unsigned int i; } v; v.f = f;
    unsigned int i = v.i;
    return (unsigned short)((i + 0x7FFFu + ((i >> 16) & 1u)) >> 16);
}

// ---------------- CSR build (XCD-sliced hist/fill) ----------------

__global__ void hist_kernel(const int* __restrict__ dst, int* __restrict__ cnt,
                            int nE, int sliceN) {
    const int slice = blockIdx.x & 7;
    const int lo = slice * sliceN, hi = lo + sliceN;
    const int nb = gridDim.x >> 3;
    const int bs = blockIdx.x >> 3;
    for (int i = bs * 256 + threadIdx.x; i < nE; i += nb * 256) {
        int d = dst[i];
        if (d >= lo && d < hi) atomicAdd(&cnt[d], 1);
    }
}

__global__ void fill_kernel(const int* __restrict__ src, const int* __restrict__ dst,
                            int* __restrict__ cnt, int* __restrict__ col_idx,
                            int nE, int sliceN) {
    const int slice = blockIdx.x & 7;
    const int lo = slice * sliceN, hi = lo + sliceN;
    const int nb = gridDim.x >> 3;
    const int bs = blockIdx.x >> 3;
    for (int i = bs * 256 + threadIdx.x; i < nE; i += nb * 256) {
        int d = dst[i];
        int s = src[i];
        if (d >= lo && d < hi) {
            int pos = atomicAdd(&cnt[d], 1);
            col_idx[pos] = s;
        }
    }
}

__global__ void blocksum_kernel(const int* __restrict__ cnt, int* __restrict__ blockSum, int n) {
    int i = blockIdx.x * 256 + threadIdx.x;
    int d = (i < n) ? cnt[i] : 0;
    int lane = threadIdx.x & 63, wid = threadIdx.x >> 6;
    __shared__ int ws[4];
    int v = d;
    for (int off = 32; off; off >>= 1) v += __shfl_down(v, off);
    if (lane == 0) ws[wid] = v;
    __syncthreads();
    if (threadIdx.x == 0) blockSum[blockIdx.x] = ws[0] + ws[1] + ws[2] + ws[3];
}

__global__ void scan_write_kernel(int* __restrict__ cnt, const int* __restrict__ blockSum,
                                  int* __restrict__ row_ptr, float* __restrict__ inv_deg,
                                  int n) {
    const int b = blockIdx.x, tid = threadIdx.x;
    const int lane = tid & 63, wid = tid >> 6;
    __shared__ int wsA[4];
    __shared__ int wsB[4];
    int v = (tid < b) ? blockSum[tid] : 0;
    for (int off = 32; off; off >>= 1) v += __shfl_down(v, off);
    if (lane == 0) wsA[wid] = v;
    int i = b * 256 + tid;
    int d = (i < n) ? cnt[i] : 0;
    int s = d;
    for (int off = 1; off < 64; off <<= 1) {
        int t = __shfl_up(s, off);
        if (lane >= off) s += t;
    }
    if (lane == 63) wsB[wid] = s;
    __syncthreads();
    int blockOff = wsA[0] + wsA[1] + wsA[2] + wsA[3];
    int wOff = 0;
    for (int w = 0; w < wid; ++w) wOff += wsB[w];
    int excl = blockOff + wOff + s - d;
    if (i < n) {
        row_ptr[i] = excl;
        cnt[i]     = excl;
        inv_deg[i] = 1.0f / (float)(d > 1 ? d : 1);
    }
    if (i == n) row_ptr[n] = excl;
}

// ---------------- conversions ----------------

// x fp32 [n][128] -> bf16 H plane [n][128]. 4 features/thread.
__global__ void xconv_kernel(const float* __restrict__ x, unsigned short* __restrict__ xc, int n) {
    int i = blockIdx.x * 256 + threadIdx.x;
    if (i >= n * 32) return;
    int node = i >> 5, fb = (i & 31) * 4;
    float4 v = *(const float4*)(x + (size_t)node * NFEAT + fb);
    uint2 hw;
    hw.x = (unsigned int)f2bf(v.x) | ((unsigned int)f2bf(v.y) << 16);
    hw.y = (unsigned int)f2bf(v.z) | ((unsigned int)f2bf(v.w) << 16);
    *(uint2*)(xc + (size_t)node * RS + fb) = hw;
}

// W -> transposed K-major cat [nout][256], H plane only, PRE-SWIZZLED:
// element (c,k) stored at c*256 + (k ^ ((c&7)<<3)).
__global__ void wconv_kernel(const float* __restrict__ Wl, const float* __restrict__ Wr,
                             unsigned short* __restrict__ Wsz, int nout) {
    int idx = blockIdx.x * 256 + threadIdx.x;
    if (idx >= nout * 256) return;
    int c = idx >> 8, k = idx & 255;
    float f = (k < 128) ? Wl[k * nout + c] : Wr[(k - 128) * nout + c];
    Wsz[c * 256 + (k ^ ((c & 7) << 3))] = f2bf(f);
}

// ---------------- mean aggregation (CSR gather, bf16 rows, uint4) ----------------
// 16 lanes/node x uint4 (8 feats per 16B load); unroll 8, 4 accum sets.
// fp32 accumulate, bf16 write.
__global__ void agg_kernel(const unsigned short* __restrict__ in,
                           const int* __restrict__ row_ptr, const int* __restrict__ col_idx,
                           const float* __restrict__ inv_deg,
                           unsigned short* __restrict__ agg, int n) {
    int lane = threadIdx.x & 15;
    int node = blockIdx.x * 16 + (threadIdx.x >> 4);
    if (node >= n) return;
    int beg = row_ptr[node], end = row_ptr[node + 1];
    float a[4][8];
    #pragma unroll
    for (int u = 0; u < 4; ++u)
        #pragma unroll
        for (int j = 0; j < 8; ++j) a[u][j] = 0.f;
    auto acc8 = [&](float* A, uint4 v) {
        A[0] += bfhi2f(v.x << 16); A[1] += bfhi2f(v.x & 0xFFFF0000u);
        A[2] += bfhi2f(v.y << 16); A[3] += bfhi2f(v.y & 0xFFFF0000u);
        A[4] += bfhi2f(v.z << 16); A[5] += bfhi2f(v.z & 0xFFFF0000u);
        A[6] += bfhi2f(v.w << 16); A[7] += bfhi2f(v.w & 0xFFFF0000u);
    };
    int e = beg;
    for (; e + 8 <= end; e += 8) {
        uint4 v[8];
        #pragma unroll
        for (int u = 0; u < 8; ++u) {
            int s = col_idx[e + u];
            v[u] = *(const uint4*)(in + (size_t)s * RS + lane * 8);
        }
        #pragma unroll
        for (int u = 0; u < 8; ++u) acc8(a[u & 3], v[u]);
    }
    for (; e < end; ++e) {
        int s = col_idx[e];
        uint4 v = *(const uint4*)(in + (size_t)s * RS + lane * 8);
        acc8(a[0], v);
    }
    float sc = inv_deg[node];
    unsigned short hs[8];
    #pragma unroll
    for (int j = 0; j < 8; ++j)
        hs[j] = f2bf(((a[0][j] + a[1][j]) + (a[2][j] + a[3][j])) * sc);
    uint4 hv;
    hv.x = (unsigned int)hs[0] | ((unsigned int)hs[1] << 16);
    hv.y = (unsigned int)hs[2] | ((unsigned int)hs[3] << 16);
    hv.z = (unsigned int)hs[4] | ((unsigned int)hs[5] << 16);
    hv.w = (unsigned int)hs[6] | ((unsigned int)hs[7] << 16);
    *(uint4*)(agg + (size_t)node * RS + lane * 8) = hv;
}

// ---------------- MFMA GEMM: C = [agg|x] @ W_hi + b, pure bf16 ----------------
// Round-12: round-11's barrier-free pipelined structure (the first to beat the
// latency wall), with the A-lo plane dropped -> pure bf16 GEMM. MFMA count and
// A traffic both halve. Error budget: +~2^-9 rel per operand over K=256 ->
// ~0.006 RMS, absmax headroom 0.0825 vs harness floor 0.0156.
//   - ONE __syncthreads total (W staged via global_load_lds, overlapped with
//     first A prefetches); barrier-free K-loop with counted vmcnt waits.
//   - Wave = 32 rows x 64 cols (4 B-frags), block = 128 rows.
//   - A depth-2 kstep prefetch (4 loads / 16 VGPR in flight).

template<int NOUT, bool RELU, bool FINAL>
__global__ __launch_bounds__(256, 3) void mfma_gemm(
    const unsigned short* __restrict__ aggc, const unsigned short* __restrict__ xc,
    const unsigned short* __restrict__ Wsz, const float* __restrict__ bias,
    float* __restrict__ outF, unsigned short* __restrict__ outC, int n, int nRowTiles)
{
    __shared__ char smem[32768];
    const int tid  = threadIdx.x;
    const int wid  = tid >> 6, lane = tid & 63;
    const int rowTileI = blockIdx.x % nRowTiles;
    const int colTile  = (blockIdx.x / nRowTiles) * 64;

    // stage W tile (64 cols x 256 k, pre-swizzled) via global_load_lds
    {
        const char* wsrc = (const char*)(Wsz + (size_t)colTile * 256);
        #pragma unroll
        for (int i = 0; i < 8; ++i) {
            const int off = i * 4096 + wid * 1024;
            __builtin_amdgcn_global_load_lds(
                (const __attribute__((address_space(1))) unsigned int*)(wsrc + off + lane * 16),
                (__attribute__((address_space(3))) unsigned int*)(smem + off),
                16, 0, 0);
        }
    }

    const int lrow = lane & 15;
    const int lk   = (lane >> 4) * 8;
    const int lkb  = (lane >> 4) * 16;

    const int rowBase = rowTileI * 128 + wid * 32;
    int r0 = rowBase + lrow;      if (r0 > n - 1) r0 = n - 1;
    int r1 = rowBase + 16 + lrow; if (r1 > n - 1) r1 = n - 1;

    const unsigned short* Ar0 = aggc + (size_t)r0 * RS;
    const unsigned short* Ar1 = aggc + (size_t)r1 * RS;
    const unsigned short* Xr0 = xc   + (size_t)r0 * RS;
    const unsigned short* Xr1 = xc   + (size_t)r1 * RS;

    // depth-2 A prefetch pipeline (slot = ks & 1)
    bf16x8 p0[2], p1[2];
    auto loadA = [&](int ks, int slot) {
        const unsigned short* P0 = (ks < 4) ? Ar0 : Xr0;
        const unsigned short* P1 = (ks < 4) ? Ar1 : Xr1;
        const int kk = (ks & 3) * 32 + lk;
        p0[slot] = *(const bf16x8*)(P0 + kk);
        p1[slot] = *(const bf16x8*)(P1 + kk);
    };
    loadA(0, 0);
    loadA(1, 1);

    // B-frag LDS addressing: byte = (cc*512 + ks*64 + lkb) ^ ((cc&7)<<4)
    int cbase[4], xmask[4];
    #pragma unroll
    for (int nf = 0; nf < 4; ++nf) {
        int cc = nf * 16 + lrow;
        cbase[nf] = (cc << 9) + lkb;
        xmask[nf] = (cc & 7) << 4;
    }

    __syncthreads();            // the ONLY barrier: W in LDS (A ks0/ks1 drain with it)

    f32x4 acc[2][4];
    #pragma unroll
    for (int mf = 0; mf < 2; ++mf)
        #pragma unroll
        for (int nf = 0; nf < 4; ++nf)
            acc[mf][nf] = (f32x4){0.f, 0.f, 0.f, 0.f};

    bf16x8 b0 = *(const bf16x8*)(smem + (cbase[0] ^ xmask[0]));
    bf16x8 b1 = *(const bf16x8*)(smem + (cbase[1] ^ xmask[1]));
    bf16x8 b2 = *(const bf16x8*)(smem + (cbase[2] ^ xmask[2]));
    bf16x8 b3 = *(const bf16x8*)(smem + (cbase[3] ^ xmask[3]));

    #pragma unroll
    for (int ks = 0; ks < 8; ++ks) {
        const int slot = ks & 1;
        const bf16x8 c0 = p0[slot], c1 = p1[slot];
        const bf16x8 d0 = b0, d1 = b1, d2 = b2, d3 = b3;
        if (ks < 6) loadA(ks + 2, slot);           // issue next-next A loads
        if (ks < 7) {                              // issue next B ds_reads
            const int ko = (ks + 1) << 6;
            b0 = *(const bf16x8*)(smem + ((cbase[0] + ko) ^ xmask[0]));
            b1 = *(const bf16x8*)(smem + ((cbase[1] + ko) ^ xmask[1]));
            b2 = *(const bf16x8*)(smem + ((cbase[2] + ko) ^ xmask[2]));
            b3 = *(const bf16x8*)(smem + ((cbase[3] + ko) ^ xmask[3]));
        }
        acc[0][0] = __builtin_amdgcn_mfma_f32_16x16x32_bf16(c0, d0, acc[0][0], 0, 0, 0);
        acc[1][0] = __builtin_amdgcn_mfma_f32_16x16x32_bf16(c1, d0, acc[1][0], 0, 0, 0);
        acc[0][1] = __builtin_amdgcn_mfma_f32_16x16x32_bf16(c0, d1, acc[0][1], 0, 0, 0);
        acc[1][1] = __builtin_amdgcn_mfma_f32_16x16x32_bf16(c1, d1, acc[1][1], 0, 0, 0);
        acc[0][2] = __builtin_amdgcn_mfma_f32_16x16x32_bf16(c0, d2, acc[0][2], 0, 0, 0);
        acc[1][2] = __builtin_amdgcn_mfma_f32_16x16x32_bf16(c1, d2, acc[1][2], 0, 0, 0);
        acc[0][3] = __builtin_amdgcn_mfma_f32_16x16x32_bf16(c0, d3, acc[0][3], 0, 0, 0);
        acc[1][3] = __builtin_amdgcn_mfma_f32_16x16x32_bf16(c1, d3, acc[1][3], 0, 0, 0);
    }

    // epilogue: bias (+ReLU); FINAL -> fp32 out, else -> bf16 H plane
    #pragma unroll
    for (int mf = 0; mf < 2; ++mf) {
        #pragma unroll
        for (int nf = 0; nf < 4; ++nf) {
            const int c = colTile + nf * 16 + lrow;
            const float bv = bias[c];
            #pragma unroll
            for (int reg = 0; reg < 4; ++reg) {
                const int r = rowBase + mf * 16 + (lane >> 4) * 4 + reg;
                if (r < n) {
                    float h = acc[mf][nf][reg] + bv;
                    if (RELU) h = fmaxf(h, 0.f);
                    if (FINAL) {
                        outF[(size_t)r * NOUT + c] = h;
                    } else {
                        outC[(size_t)r * RS + c] = f2bf(h);
                    }
                }
            }
        }
    }
}

extern "C" void kernel_launch(void* const* d_in, const int* in_sizes, int n_in,
                              void* d_out, int out_size, void* d_ws, size_t ws_size,
                              hipStream_t stream) {
    const float* x   = (const float*)d_in[0];
    const int*   ei  = (const int*)d_in[1];
    const float* Wl0 = (const float*)d_in[2];
    const float* Wr0 = (const float*)d_in[3];
    const float* b0  = (const float*)d_in[4];
    const float* Wl1 = (const float*)d_in[5];
    const float* Wr1 = (const float*)d_in[6];
    const float* b1  = (const float*)d_in[7];
    const float* Wl2 = (const float*)d_in[8];
    const float* Wr2 = (const float*)d_in[9];
    const float* b2  = (const float*)d_in[10];

    const int nN = in_sizes[0] / NFEAT;       // 50000
    const int nE = in_sizes[1] / 2;           // 800000
    const int* src = ei;
    const int* dst = ei + nE;

    char* ws = (char*)d_ws;
    size_t off = 0;
    auto take = [&](size_t bytes) { char* p = ws + off; off += (bytes + 255) & ~(size_t)255; return p; };
    int*   cnt      = (int*)  take((size_t)nN * 4);
    int*   row_ptr  = (int*)  take((size_t)(nN + 1) * 4);
    int*   col_idx  = (int*)  take((size_t)nE * 4);
    float* inv_deg  = (float*)take((size_t)nN * 4);
    int*   blockSum = (int*)  take(256 * 4);
    const size_t plane = (size_t)nN * RS * 2;             // 12.8 MB bf16 plane
    unsigned short* aggC = (unsigned short*)take(plane);
    unsigned short* xc0  = (unsigned short*)take(plane);
    unsigned short* xc1  = (unsigned short*)take(plane);
    unsigned short* Wsz0 = (unsigned short*)take(128 * 256 * 2);
    unsigned short* Wsz1 = (unsigned short*)take(128 * 256 * 2);
    unsigned short* Wsz2 = (unsigned short*)take(64 * 256 * 2);
    (void)ws_size; (void)n_in; (void)out_size;

    const int scanBlocks = (nN + 255) / 256;
    const int sliceN = (nN + 7) / 8;

    // CSR build (XCD-sliced hist/fill)
    hipMemsetAsync(cnt, 0, (size_t)nN * 4, stream);
    hist_kernel<<<2048, 256, 0, stream>>>(dst, cnt, nE, sliceN);
    blocksum_kernel<<<scanBlocks, 256, 0, stream>>>(cnt, blockSum, nN);
    scan_write_kernel<<<scanBlocks, 256, 0, stream>>>(cnt, blockSum, row_ptr, inv_deg, nN);
    fill_kernel<<<2048, 256, 0, stream>>>(src, dst, cnt, col_idx, nE, sliceN);

    // conversions
    xconv_kernel<<<(nN * 32 + 255) / 256, 256, 0, stream>>>(x, xc0, nN);
    wconv_kernel<<<(128 * 256 + 255) / 256, 256, 0, stream>>>(Wl0, Wr0, Wsz0, 128);
    wconv_kernel<<<(128 * 256 + 255) / 256, 256, 0, stream>>>(Wl1, Wr1, Wsz1, 128);
    wconv_kernel<<<(64 * 256 + 255) / 256, 256, 0, stream>>>(Wl2, Wr2, Wsz2, 64);

    const int aggGrid   = (nN + 15) / 16;
    const int nRowTiles = (nN + 127) / 128;   // 391 (128 rows per block)
    const int gBig = nRowTiles * 2;           // NOUT=128: two 64-col tiles
    const int gFin = nRowTiles;               // NOUT=64: one col tile

    // layer 0: x -> h0
    agg_kernel<<<aggGrid, 256, 0, stream>>>(xc0, row_ptr, col_idx, inv_deg, aggC, nN);
    mfma_gemm<128, true, false><<<gBig, 256, 0, stream>>>(
        aggC, xc0, Wsz0, b0, nullptr, xc1, nN, nRowTiles);
    // layer 1: h0 -> h1
    agg_kernel<<<aggGrid, 256, 0, stream>>>(xc1, row_ptr, col_idx, inv_deg, aggC, nN);
    mfma_gemm<128, true, false><<<gBig, 256, 0, stream>>>(
        aggC, xc1, Wsz1, b1, nullptr, xc0, nN, nRowTiles);
    // layer 2: h1 -> out (fp32)
    agg_kernel<<<aggGrid, 256, 0, stream>>>(xc0, row_ptr, col_idx, inv_deg, aggC, nN);
    mfma_gemm<64, false, true><<<gFin, 256, 0, stream>>>(
        aggC, xc0, Wsz2, b2, (float*)d_out, nullptr, nN, nRowTiles);
}

// Round 13
// 246.831 us; speedup vs baseline: 1.2764x; 1.0195x over previous
//
#include <hip/hip_runtime.h>

#define NFEAT 128
#define RS 128   // bf16 H-plane row stride in shorts

using bf16x8 = __attribute__((ext_vector_type(8))) short;
using f32x4  = __attribute__((ext_vector_type(4))) float;

__device__ __forceinline__ float bf2f(unsigned short u) {
    union { unsigned int i; float f; } v; v.i = ((unsigned int)u) << 16; return v.f;
}
__device__ __forceinline__ float bfhi2f(unsigned int hi16) {
    union { unsigned int i; float f; } v; v.i = hi16; return v.f;
}
__device__ __forceinline__ unsigned short f2bf(float f) {      // RNE
    union { float f; unsigned int i; } v; v.f = f;
    unsigned int i = v.i;
    return (unsigned short)((i + 0x7FFFu + ((i >> 16) & 1u)) >> 16);
}

// ---------------- CSR build (XCD-sliced hist/fill) ----------------

// Round-13: hipMemsetAsync's small-buffer fill path measured 42.5us @ 5GB/s for
// 200KB (20x slower than its large-fill rate). Trivial custom zero kernel ~2us.
__global__ void zero_kernel(int* __restrict__ p, int n) {
    int i = blockIdx.x * 256 + threadIdx.x;
    if (i < n) p[i] = 0;
}

__global__ void hist_kernel(const int* __restrict__ dst, int* __restrict__ cnt,
                            int nE, int sliceN) {
    const int slice = blockIdx.x & 7;
    const int lo = slice * sliceN, hi = lo + sliceN;
    const int nb = gridDim.x >> 3;
    const int bs = blockIdx.x >> 3;
    for (int i = bs * 256 + threadIdx.x; i < nE; i += nb * 256) {
        int d = dst[i];
        if (d >= lo && d < hi) atomicAdd(&cnt[d], 1);
    }
}

__global__ void fill_kernel(const int* __restrict__ src, const int* __restrict__ dst,
                            int* __restrict__ cnt, int* __restrict__ col_idx,
                            int nE, int sliceN) {
    const int slice = blockIdx.x & 7;
    const int lo = slice * sliceN, hi = lo + sliceN;
    const int nb = gridDim.x >> 3;
    const int bs = blockIdx.x >> 3;
    for (int i = bs * 256 + threadIdx.x; i < nE; i += nb * 256) {
        int d = dst[i];
        int s = src[i];
        if (d >= lo && d < hi) {
            int pos = atomicAdd(&cnt[d], 1);
            col_idx[pos] = s;
        }
    }
}

__global__ void blocksum_kernel(const int* __restrict__ cnt, int* __restrict__ blockSum, int n) {
    int i = blockIdx.x * 256 + threadIdx.x;
    int d = (i < n) ? cnt[i] : 0;
    int lane = threadIdx.x & 63, wid = threadIdx.x >> 6;
    __shared__ int ws[4];
    int v = d;
    for (int off = 32; off; off >>= 1) v += __shfl_down(v, off);
    if (lane == 0) ws[wid] = v;
    __syncthreads();
    if (threadIdx.x == 0) blockSum[blockIdx.x] = ws[0] + ws[1] + ws[2] + ws[3];
}

__global__ void scan_write_kernel(int* __restrict__ cnt, const int* __restrict__ blockSum,
                                  int* __restrict__ row_ptr, float* __restrict__ inv_deg,
                                  int n) {
    const int b = blockIdx.x, tid = threadIdx.x;
    const int lane = tid & 63, wid = tid >> 6;
    __shared__ int wsA[4];
    __shared__ int wsB[4];
    int v = (tid < b) ? blockSum[tid] : 0;
    for (int off = 32; off; off >>= 1) v += __shfl_down(v, off);
    if (lane == 0) wsA[wid] = v;
    int i = b * 256 + tid;
    int d = (i < n) ? cnt[i] : 0;
    int s = d;
    for (int off = 1; off < 64; off <<= 1) {
        int t = __shfl_up(s, off);
        if (lane >= off) s += t;
    }
    if (lane == 63) wsB[wid] = s;
    __syncthreads();
    int blockOff = wsA[0] + wsA[1] + wsA[2] + wsA[3];
    int wOff = 0;
    for (int w = 0; w < wid; ++w) wOff += wsB[w];
    int excl = blockOff + wOff + s - d;
    if (i < n) {
        row_ptr[i] = excl;
        cnt[i]     = excl;
        inv_deg[i] = 1.0f / (float)(d > 1 ? d : 1);
    }
    if (i == n) row_ptr[n] = excl;
}

// ---------------- conversions ----------------

// x fp32 [n][128] -> bf16 H plane [n][128]. 4 features/thread.
__global__ void xconv_kernel(const float* __restrict__ x, unsigned short* __restrict__ xc, int n) {
    int i = blockIdx.x * 256 + threadIdx.x;
    if (i >= n * 32) return;
    int node = i >> 5, fb = (i & 31) * 4;
    float4 v = *(const float4*)(x + (size_t)node * NFEAT + fb);
    uint2 hw;
    hw.x = (unsigned int)f2bf(v.x) | ((unsigned int)f2bf(v.y) << 16);
    hw.y = (unsigned int)f2bf(v.z) | ((unsigned int)f2bf(v.w) << 16);
    *(uint2*)(xc + (size_t)node * RS + fb) = hw;
}

// All three W -> transposed K-major [nout][256] bf16, pre-swizzled, ONE launch.
// element (c,k) stored at c*256 + (k ^ ((c&7)<<3)).
__global__ void wconv_all_kernel(const float* __restrict__ Wl0, const float* __restrict__ Wr0,
                                 const float* __restrict__ Wl1, const float* __restrict__ Wr1,
                                 const float* __restrict__ Wl2, const float* __restrict__ Wr2,
                                 unsigned short* __restrict__ Wsz0,
                                 unsigned short* __restrict__ Wsz1,
                                 unsigned short* __restrict__ Wsz2) {
    int idx = blockIdx.x * 256 + threadIdx.x;
    // layout: [0, 32768) -> W0; [32768, 65536) -> W1; [65536, 81920) -> W2
    const float* Wl; const float* Wr; unsigned short* Wsz; int nout; int li;
    if (idx < 32768)      { Wl = Wl0; Wr = Wr0; Wsz = Wsz0; nout = 128; li = idx; }
    else if (idx < 65536) { Wl = Wl1; Wr = Wr1; Wsz = Wsz1; nout = 128; li = idx - 32768; }
    else if (idx < 81920) { Wl = Wl2; Wr = Wr2; Wsz = Wsz2; nout = 64;  li = idx - 65536; }
    else return;
    int c = li >> 8, k = li & 255;
    float f = (k < 128) ? Wl[k * nout + c] : Wr[(k - 128) * nout + c];
    Wsz[c * 256 + (k ^ ((c & 7) << 3))] = f2bf(f);
}

// ---------------- mean aggregation (CSR gather, bf16 rows, uint4) ----------------
__global__ void agg_kernel(const unsigned short* __restrict__ in,
                           const int* __restrict__ row_ptr, const int* __restrict__ col_idx,
                           const float* __restrict__ inv_deg,
                           unsigned short* __restrict__ agg, int n) {
    int lane = threadIdx.x & 15;
    int node = blockIdx.x * 16 + (threadIdx.x >> 4);
    if (node >= n) return;
    int beg = row_ptr[node], end = row_ptr[node + 1];
    float a[4][8];
    #pragma unroll
    for (int u = 0; u < 4; ++u)
        #pragma unroll
        for (int j = 0; j < 8; ++j) a[u][j] = 0.f;
    auto acc8 = [&](float* A, uint4 v) {
        A[0] += bfhi2f(v.x << 16); A[1] += bfhi2f(v.x & 0xFFFF0000u);
        A[2] += bfhi2f(v.y << 16); A[3] += bfhi2f(v.y & 0xFFFF0000u);
        A[4] += bfhi2f(v.z << 16); A[5] += bfhi2f(v.z & 0xFFFF0000u);
        A[6] += bfhi2f(v.w << 16); A[7] += bfhi2f(v.w & 0xFFFF0000u);
    };
    int e = beg;
    for (; e + 8 <= end; e += 8) {
        uint4 v[8];
        #pragma unroll
        for (int u = 0; u < 8; ++u) {
            int s = col_idx[e + u];
            v[u] = *(const uint4*)(in + (size_t)s * RS + lane * 8);
        }
        #pragma unroll
        for (int u = 0; u < 8; ++u) acc8(a[u & 3], v[u]);
    }
    for (; e < end; ++e) {
        int s = col_idx[e];
        uint4 v = *(const uint4*)(in + (size_t)s * RS + lane * 8);
        acc8(a[0], v);
    }
    float sc = inv_deg[node];
    unsigned short hs[8];
    #pragma unroll
    for (int j = 0; j < 8; ++j)
        hs[j] = f2bf(((a[0][j] + a[1][j]) + (a[2][j] + a[3][j])) * sc);
    uint4 hv;
    hv.x = (unsigned int)hs[0] | ((unsigned int)hs[1] << 16);
    hv.y = (unsigned int)hs[2] | ((unsigned int)hs[3] << 16);
    hv.z = (unsigned int)hs[4] | ((unsigned int)hs[5] << 16);
    hv.w = (unsigned int)hs[6] | ((unsigned int)hs[7] << 16);
    *(uint4*)(agg + (size_t)node * RS + lane * 8) = hv;
}

// ---------------- MFMA GEMM: C = [agg|x] @ W_hi + b, pure bf16 ----------------
// Round-11/12 structure (frozen): barrier-free pipelined K-loop, one
// __syncthreads (W staged via global_load_lds overlapping first A prefetches),
// wave = 32 rows x 64 cols, depth-2 A prefetch.

template<int NOUT, bool RELU, bool FINAL>
__global__ __launch_bounds__(256, 3) void mfma_gemm(
    const unsigned short* __restrict__ aggc, const unsigned short* __restrict__ xc,
    const unsigned short* __restrict__ Wsz, const float* __restrict__ bias,
    float* __restrict__ outF, unsigned short* __restrict__ outC, int n, int nRowTiles)
{
    __shared__ char smem[32768];
    const int tid  = threadIdx.x;
    const int wid  = tid >> 6, lane = tid & 63;
    const int rowTileI = blockIdx.x % nRowTiles;
    const int colTile  = (blockIdx.x / nRowTiles) * 64;

    // stage W tile (64 cols x 256 k, pre-swizzled) via global_load_lds
    {
        const char* wsrc = (const char*)(Wsz + (size_t)colTile * 256);
        #pragma unroll
        for (int i = 0; i < 8; ++i) {
            const int off = i * 4096 + wid * 1024;
            __builtin_amdgcn_global_load_lds(
                (const __attribute__((address_space(1))) unsigned int*)(wsrc + off + lane * 16),
                (__attribute__((address_space(3))) unsigned int*)(smem + off),
                16, 0, 0);
        }
    }

    const int lrow = lane & 15;
    const int lk   = (lane >> 4) * 8;
    const int lkb  = (lane >> 4) * 16;

    const int rowBase = rowTileI * 128 + wid * 32;
    int r0 = rowBase + lrow;      if (r0 > n - 1) r0 = n - 1;
    int r1 = rowBase + 16 + lrow; if (r1 > n - 1) r1 = n - 1;

    const unsigned short* Ar0 = aggc + (size_t)r0 * RS;
    const unsigned short* Ar1 = aggc + (size_t)r1 * RS;
    const unsigned short* Xr0 = xc   + (size_t)r0 * RS;
    const unsigned short* Xr1 = xc   + (size_t)r1 * RS;

    // depth-2 A prefetch pipeline (slot = ks & 1)
    bf16x8 p0[2], p1[2];
    auto loadA = [&](int ks, int slot) {
        const unsigned short* P0 = (ks < 4) ? Ar0 : Xr0;
        const unsigned short* P1 = (ks < 4) ? Ar1 : Xr1;
        const int kk = (ks & 3) * 32 + lk;
        p0[slot] = *(const bf16x8*)(P0 + kk);
        p1[slot] = *(const bf16x8*)(P1 + kk);
    };
    loadA(0, 0);
    loadA(1, 1);

    // B-frag LDS addressing: byte = (cc*512 + ks*64 + lkb) ^ ((cc&7)<<4)
    int cbase[4], xmask[4];
    #pragma unroll
    for (int nf = 0; nf < 4; ++nf) {
        int cc = nf * 16 + lrow;
        cbase[nf] = (cc << 9) + lkb;
        xmask[nf] = (cc & 7) << 4;
    }

    __syncthreads();            // the ONLY barrier

    f32x4 acc[2][4];
    #pragma unroll
    for (int mf = 0; mf < 2; ++mf)
        #pragma unroll
        for (int nf = 0; nf < 4; ++nf)
            acc[mf][nf] = (f32x4){0.f, 0.f, 0.f, 0.f};

    bf16x8 b0 = *(const bf16x8*)(smem + (cbase[0] ^ xmask[0]));
    bf16x8 b1 = *(const bf16x8*)(smem + (cbase[1] ^ xmask[1]));
    bf16x8 b2 = *(const bf16x8*)(smem + (cbase[2] ^ xmask[2]));
    bf16x8 b3 = *(const bf16x8*)(smem + (cbase[3] ^ xmask[3]));

    #pragma unroll
    for (int ks = 0; ks < 8; ++ks) {
        const int slot = ks & 1;
        const bf16x8 c0 = p0[slot], c1 = p1[slot];
        const bf16x8 d0 = b0, d1 = b1, d2 = b2, d3 = b3;
        if (ks < 6) loadA(ks + 2, slot);           // issue next-next A loads
        if (ks < 7) {                              // issue next B ds_reads
            const int ko = (ks + 1) << 6;
            b0 = *(const bf16x8*)(smem + ((cbase[0] + ko) ^ xmask[0]));
            b1 = *(const bf16x8*)(smem + ((cbase[1] + ko) ^ xmask[1]));
            b2 = *(const bf16x8*)(smem + ((cbase[2] + ko) ^ xmask[2]));
            b3 = *(const bf16x8*)(smem + ((cbase[3] + ko) ^ xmask[3]));
        }
        acc[0][0] = __builtin_amdgcn_mfma_f32_16x16x32_bf16(c0, d0, acc[0][0], 0, 0, 0);
        acc[1][0] = __builtin_amdgcn_mfma_f32_16x16x32_bf16(c1, d0, acc[1][0], 0, 0, 0);
        acc[0][1] = __builtin_amdgcn_mfma_f32_16x16x32_bf16(c0, d1, acc[0][1], 0, 0, 0);
        acc[1][1] = __builtin_amdgcn_mfma_f32_16x16x32_bf16(c1, d1, acc[1][1], 0, 0, 0);
        acc[0][2] = __builtin_amdgcn_mfma_f32_16x16x32_bf16(c0, d2, acc[0][2], 0, 0, 0);
        acc[1][2] = __builtin_amdgcn_mfma_f32_16x16x32_bf16(c1, d2, acc[1][2], 0, 0, 0);
        acc[0][3] = __builtin_amdgcn_mfma_f32_16x16x32_bf16(c0, d3, acc[0][3], 0, 0, 0);
        acc[1][3] = __builtin_amdgcn_mfma_f32_16x16x32_bf16(c1, d3, acc[1][3], 0, 0, 0);
    }

    // epilogue: bias (+ReLU); FINAL -> fp32 out, else -> bf16 H plane
    #pragma unroll
    for (int mf = 0; mf < 2; ++mf) {
        #pragma unroll
        for (int nf = 0; nf < 4; ++nf) {
            const int c = colTile + nf * 16 + lrow;
            const float bv = bias[c];
            #pragma unroll
            for (int reg = 0; reg < 4; ++reg) {
                const int r = rowBase + mf * 16 + (lane >> 4) * 4 + reg;
                if (r < n) {
                    float h = acc[mf][nf][reg] + bv;
                    if (RELU) h = fmaxf(h, 0.f);
                    if (FINAL) {
                        outF[(size_t)r * NOUT + c] = h;
                    } else {
                        outC[(size_t)r * RS + c] = f2bf(h);
                    }
                }
            }
        }
    }
}

extern "C" void kernel_launch(void* const* d_in, const int* in_sizes, int n_in,
                              void* d_out, int out_size, void* d_ws, size_t ws_size,
                              hipStream_t stream) {
    const float* x   = (const float*)d_in[0];
    const int*   ei  = (const int*)d_in[1];
    const float* Wl0 = (const float*)d_in[2];
    const float* Wr0 = (const float*)d_in[3];
    const float* b0  = (const float*)d_in[4];
    const float* Wl1 = (const float*)d_in[5];
    const float* Wr1 = (const float*)d_in[6];
    const float* b1  = (const float*)d_in[7];
    const float* Wl2 = (const float*)d_in[8];
    const float* Wr2 = (const float*)d_in[9];
    const float* b2  = (const float*)d_in[10];

    const int nN = in_sizes[0] / NFEAT;       // 50000
    const int nE = in_sizes[1] / 2;           // 800000
    const int* src = ei;
    const int* dst = ei + nE;

    char* ws = (char*)d_ws;
    size_t off = 0;
    auto take = [&](size_t bytes) { char* p = ws + off; off += (bytes + 255) & ~(size_t)255; return p; };
    int*   cnt      = (int*)  take((size_t)nN * 4);
    int*   row_ptr  = (int*)  take((size_t)(nN + 1) * 4);
    int*   col_idx  = (int*)  take((size_t)nE * 4);
    float* inv_deg  = (float*)take((size_t)nN * 4);
    int*   blockSum = (int*)  take(256 * 4);
    const size_t plane = (size_t)nN * RS * 2;             // 12.8 MB bf16 plane
    unsigned short* aggC = (unsigned short*)take(plane);
    unsigned short* xc0  = (unsigned short*)take(plane);
    unsigned short* xc1  = (unsigned short*)take(plane);
    unsigned short* Wsz0 = (unsigned short*)take(128 * 256 * 2);
    unsigned short* Wsz1 = (unsigned short*)take(128 * 256 * 2);
    unsigned short* Wsz2 = (unsigned short*)take(64 * 256 * 2);
    (void)ws_size; (void)n_in; (void)out_size;

    const int scanBlocks = (nN + 255) / 256;
    const int sliceN = (nN + 7) / 8;

    // CSR build (XCD-sliced hist/fill; custom zero kernel -- round-13)
    zero_kernel<<<scanBlocks, 256, 0, stream>>>(cnt, nN);
    hist_kernel<<<2048, 256, 0, stream>>>(dst, cnt, nE, sliceN);
    blocksum_kernel<<<scanBlocks, 256, 0, stream>>>(cnt, blockSum, nN);
    scan_write_kernel<<<scanBlocks, 256, 0, stream>>>(cnt, blockSum, row_ptr, inv_deg, nN);
    fill_kernel<<<2048, 256, 0, stream>>>(src, dst, cnt, col_idx, nE, sliceN);

    // conversions (batched)
    xconv_kernel<<<(nN * 32 + 255) / 256, 256, 0, stream>>>(x, xc0, nN);
    wconv_all_kernel<<<(81920 + 255) / 256, 256, 0, stream>>>(
        Wl0, Wr0, Wl1, Wr1, Wl2, Wr2, Wsz0, Wsz1, Wsz2);

    const int aggGrid   = (nN + 15) / 16;
    const int nRowTiles = (nN + 127) / 128;   // 391 (128 rows per block)
    const int gBig = nRowTiles * 2;           // NOUT=128: two 64-col tiles
    const int gFin = nRowTiles;               // NOUT=64: one col tile

    // layer 0: x -> h0
    agg_kernel<<<aggGrid, 256, 0, stream>>>(xc0, row_ptr, col_idx, inv_deg, aggC, nN);
    mfma_gemm<128, true, false><<<gBig, 256, 0, stream>>>(
        aggC, xc0, Wsz0, b0, nullptr, xc1, nN, nRowTiles);
    // layer 1: h0 -> h1
    agg_kernel<<<aggGrid, 256, 0, stream>>>(xc1, row_ptr, col_idx, inv_deg, aggC, nN);
    mfma_gemm<128, true, false><<<gBig, 256, 0, stream>>>(
        aggC, xc1, Wsz1, b1, nullptr, xc0, nN, nRowTiles);
    // layer 2: h1 -> out (fp32)
    agg_kernel<<<aggGrid, 256, 0, stream>>>(xc0, row_ptr, col_idx, inv_deg, aggC, nN);
    mfma_gemm<64, false, true><<<gFin, 256, 0, stream>>>(
        aggC, xc0, Wsz2, b2, (float*)d_out, nullptr, nN, nRowTiles);
}

// Round 14
// 215.658 us; speedup vs baseline: 1.4610x; 1.1445x over previous
//
#include <hip/hip_runtime.h>

#define NFEAT 128
#define RS 128   // bf16 H-plane row stride in shorts

using bf16x8 = __attribute__((ext_vector_type(8))) short;
using f32x4  = __attribute__((ext_vector_type(4))) float;
using f32x2  = __attribute__((ext_vector_type(2))) float;

__device__ __forceinline__ float bf2f(unsigned short u) {
    union { unsigned int i; float f; } v; v.i = ((unsigned int)u) << 16; return v.f;
}
__device__ __forceinline__ float bfhi2f(unsigned int hi16) {
    union { unsigned int i; float f; } v; v.i = hi16; return v.f;
}
__device__ __forceinline__ unsigned short f2bf(float f) {      // RNE
    union { float f; unsigned int i; } v; v.f = f;
    unsigned int i = v.i;
    return (unsigned short)((i + 0x7FFFu + ((i >> 16) & 1u)) >> 16);
}
// pack 4 f32 -> 4 OCP e4m3 bytes (RNE, saturating)
__device__ __forceinline__ unsigned int f4_to_fp8x4(float f0, float f1, float f2, float f3) {
    int p = __builtin_amdgcn_cvt_pk_fp8_f32(f0, f1, 0, false);
    p     = __builtin_amdgcn_cvt_pk_fp8_f32(f2, f3, p, true);
    return (unsigned int)p;
}

// ---------------- CSR build (XCD-sliced hist/fill) ----------------

__global__ void zero_kernel(int* __restrict__ p, int n) {
    int i = blockIdx.x * 256 + threadIdx.x;
    if (i < n) p[i] = 0;
}

__global__ void hist_kernel(const int* __restrict__ dst, int* __restrict__ cnt,
                            int nE, int sliceN) {
    const int slice = blockIdx.x & 7;
    const int lo = slice * sliceN, hi = lo + sliceN;
    const int nb = gridDim.x >> 3;
    const int bs = blockIdx.x >> 3;
    for (int i = bs * 256 + threadIdx.x; i < nE; i += nb * 256) {
        int d = dst[i];
        if (d >= lo && d < hi) atomicAdd(&cnt[d], 1);
    }
}

__global__ void fill_kernel(const int* __restrict__ src, const int* __restrict__ dst,
                            int* __restrict__ cnt, int* __restrict__ col_idx,
                            int nE, int sliceN) {
    const int slice = blockIdx.x & 7;
    const int lo = slice * sliceN, hi = lo + sliceN;
    const int nb = gridDim.x >> 3;
    const int bs = blockIdx.x >> 3;
    for (int i = bs * 256 + threadIdx.x; i < nE; i += nb * 256) {
        int d = dst[i];
        int s = src[i];
        if (d >= lo && d < hi) {
            int pos = atomicAdd(&cnt[d], 1);
            col_idx[pos] = s;
        }
    }
}

__global__ void blocksum_kernel(const int* __restrict__ cnt, int* __restrict__ blockSum, int n) {
    int i = blockIdx.x * 256 + threadIdx.x;
    int d = (i < n) ? cnt[i] : 0;
    int lane = threadIdx.x & 63, wid = threadIdx.x >> 6;
    __shared__ int ws[4];
    int v = d;
    for (int off = 32; off; off >>= 1) v += __shfl_down(v, off);
    if (lane == 0) ws[wid] = v;
    __syncthreads();
    if (threadIdx.x == 0) blockSum[blockIdx.x] = ws[0] + ws[1] + ws[2] + ws[3];
}

__global__ void scan_write_kernel(int* __restrict__ cnt, const int* __restrict__ blockSum,
                                  int* __restrict__ row_ptr, float* __restrict__ inv_deg,
                                  int n) {
    const int b = blockIdx.x, tid = threadIdx.x;
    const int lane = tid & 63, wid = tid >> 6;
    __shared__ int wsA[4];
    __shared__ int wsB[4];
    int v = (tid < b) ? blockSum[tid] : 0;
    for (int off = 32; off; off >>= 1) v += __shfl_down(v, off);
    if (lane == 0) wsA[wid] = v;
    int i = b * 256 + tid;
    int d = (i < n) ? cnt[i] : 0;
    int s = d;
    for (int off = 1; off < 64; off <<= 1) {
        int t = __shfl_up(s, off);
        if (lane >= off) s += t;
    }
    if (lane == 63) wsB[wid] = s;
    __syncthreads();
    int blockOff = wsA[0] + wsA[1] + wsA[2] + wsA[3];
    int wOff = 0;
    for (int w = 0; w < wid; ++w) wOff += wsB[w];
    int excl = blockOff + wOff + s - d;
    if (i < n) {
        row_ptr[i] = excl;
        cnt[i]     = excl;
        inv_deg[i] = 1.0f / (float)(d > 1 ? d : 1);
    }
    if (i == n) row_ptr[n] = excl;
}

// ---------------- conversions ----------------

// x fp32 [n][128] -> bf16 plane + fp8 shadow plane. 4 features/thread.
__global__ void xconv_kernel(const float* __restrict__ x, unsigned short* __restrict__ xc,
                             unsigned char* __restrict__ xq, int n) {
    int i = blockIdx.x * 256 + threadIdx.x;
    if (i >= n * 32) return;
    int node = i >> 5, fb = (i & 31) * 4;
    float4 v = *(const float4*)(x + (size_t)node * NFEAT + fb);
    uint2 hw;
    hw.x = (unsigned int)f2bf(v.x) | ((unsigned int)f2bf(v.y) << 16);
    hw.y = (unsigned int)f2bf(v.z) | ((unsigned int)f2bf(v.w) << 16);
    *(uint2*)(xc + (size_t)node * RS + fb) = hw;
    *(unsigned int*)(xq + (size_t)node * NFEAT + fb) = f4_to_fp8x4(v.x, v.y, v.z, v.w);
}

// All three W -> transposed K-major [nout][256] bf16, pre-swizzled, ONE launch.
__global__ void wconv_all_kernel(const float* __restrict__ Wl0, const float* __restrict__ Wr0,
                                 const float* __restrict__ Wl1, const float* __restrict__ Wr1,
                                 const float* __restrict__ Wl2, const float* __restrict__ Wr2,
                                 unsigned short* __restrict__ Wsz0,
                                 unsigned short* __restrict__ Wsz1,
                                 unsigned short* __restrict__ Wsz2) {
    int idx = blockIdx.x * 256 + threadIdx.x;
    const float* Wl; const float* Wr; unsigned short* Wsz; int nout; int li;
    if (idx < 32768)      { Wl = Wl0; Wr = Wr0; Wsz = Wsz0; nout = 128; li = idx; }
    else if (idx < 65536) { Wl = Wl1; Wr = Wr1; Wsz = Wsz1; nout = 128; li = idx - 32768; }
    else if (idx < 81920) { Wl = Wl2; Wr = Wr2; Wsz = Wsz2; nout = 64;  li = idx - 65536; }
    else return;
    int c = li >> 8, k = li & 255;
    float f = (k < 128) ? Wl[k * nout + c] : Wr[(k - 128) * nout + c];
    Wsz[c * 256 + (k ^ ((c & 7) << 3))] = f2bf(f);
}

// ---------------- mean aggregation (CSR gather, fp8 shadow plane) ----------------
// Round-14: gather from the fp8 e4m3 shadow (128 B/row -- half of bf16);
// 8 lanes/node x uint4 = 16 fp8 features per load -> VMEM instruction count
// also halves. fp32 accumulate (decode via v_cvt_pk_f32_fp8), bf16 write for
// the GEMM A-side. Error budget: ~0.005 RMS added through the Wl dot.
__global__ void agg_kernel(const unsigned char* __restrict__ xq,
                           const int* __restrict__ row_ptr, const int* __restrict__ col_idx,
                           const float* __restrict__ inv_deg,
                           unsigned short* __restrict__ agg, int n) {
    int lane = threadIdx.x & 7;                      // feature block [lane*16, lane*16+16)
    int node = blockIdx.x * 32 + (threadIdx.x >> 3);
    if (node >= n) return;
    int beg = row_ptr[node], end = row_ptr[node + 1];
    float a[4][16];
    #pragma unroll
    for (int u = 0; u < 4; ++u)
        #pragma unroll
        for (int j = 0; j < 16; ++j) a[u][j] = 0.f;
    auto acc16 = [&](float* A, uint4 v) {
        f32x2 d;
        d = __builtin_amdgcn_cvt_pk_f32_fp8(v.x, false); A[0]  += d[0]; A[1]  += d[1];
        d = __builtin_amdgcn_cvt_pk_f32_fp8(v.x, true);  A[2]  += d[0]; A[3]  += d[1];
        d = __builtin_amdgcn_cvt_pk_f32_fp8(v.y, false); A[4]  += d[0]; A[5]  += d[1];
        d = __builtin_amdgcn_cvt_pk_f32_fp8(v.y, true);  A[6]  += d[0]; A[7]  += d[1];
        d = __builtin_amdgcn_cvt_pk_f32_fp8(v.z, false); A[8]  += d[0]; A[9]  += d[1];
        d = __builtin_amdgcn_cvt_pk_f32_fp8(v.z, true);  A[10] += d[0]; A[11] += d[1];
        d = __builtin_amdgcn_cvt_pk_f32_fp8(v.w, false); A[12] += d[0]; A[13] += d[1];
        d = __builtin_amdgcn_cvt_pk_f32_fp8(v.w, true);  A[14] += d[0]; A[15] += d[1];
    };
    int e = beg;
    for (; e + 8 <= end; e += 8) {
        uint4 v[8];
        #pragma unroll
        for (int u = 0; u < 8; ++u) {
            int s = col_idx[e + u];
            v[u] = *(const uint4*)(xq + (size_t)s * NFEAT + lane * 16);
        }
        #pragma unroll
        for (int u = 0; u < 8; ++u) acc16(a[u & 3], v[u]);
    }
    for (; e < end; ++e) {
        int s = col_idx[e];
        uint4 v = *(const uint4*)(xq + (size_t)s * NFEAT + lane * 16);
        acc16(a[0], v);
    }
    float sc = inv_deg[node];
    unsigned short hs[16];
    #pragma unroll
    for (int j = 0; j < 16; ++j)
        hs[j] = f2bf(((a[0][j] + a[1][j]) + (a[2][j] + a[3][j])) * sc);
    uint4 h0, h1;
    h0.x = (unsigned int)hs[0]  | ((unsigned int)hs[1]  << 16);
    h0.y = (unsigned int)hs[2]  | ((unsigned int)hs[3]  << 16);
    h0.z = (unsigned int)hs[4]  | ((unsigned int)hs[5]  << 16);
    h0.w = (unsigned int)hs[6]  | ((unsigned int)hs[7]  << 16);
    h1.x = (unsigned int)hs[8]  | ((unsigned int)hs[9]  << 16);
    h1.y = (unsigned int)hs[10] | ((unsigned int)hs[11] << 16);
    h1.z = (unsigned int)hs[12] | ((unsigned int)hs[13] << 16);
    h1.w = (unsigned int)hs[14] | ((unsigned int)hs[15] << 16);
    *(uint4*)(agg + (size_t)node * RS + lane * 16)     = h0;
    *(uint4*)(agg + (size_t)node * RS + lane * 16 + 8) = h1;
}

// ---------------- MFMA GEMM: C = [agg|x] @ W_hi + b, pure bf16 ----------------
// Round-11/12 structure (frozen). Round-14: non-FINAL epilogue also writes the
// fp8 shadow plane for the next layer's aggregation gather.

template<int NOUT, bool RELU, bool FINAL>
__global__ __launch_bounds__(256, 3) void mfma_gemm(
    const unsigned short* __restrict__ aggc, const unsigned short* __restrict__ xc,
    const unsigned short* __restrict__ Wsz, const float* __restrict__ bias,
    float* __restrict__ outF, unsigned short* __restrict__ outC,
    unsigned char* __restrict__ outQ, int n, int nRowTiles)
{
    __shared__ char smem[32768];
    const int tid  = threadIdx.x;
    const int wid  = tid >> 6, lane = tid & 63;
    const int rowTileI = blockIdx.x % nRowTiles;
    const int colTile  = (blockIdx.x / nRowTiles) * 64;

    // stage W tile (64 cols x 256 k, pre-swizzled) via global_load_lds
    {
        const char* wsrc = (const char*)(Wsz + (size_t)colTile * 256);
        #pragma unroll
        for (int i = 0; i < 8; ++i) {
            const int off = i * 4096 + wid * 1024;
            __builtin_amdgcn_global_load_lds(
                (const __attribute__((address_space(1))) unsigned int*)(wsrc + off + lane * 16),
                (__attribute__((address_space(3))) unsigned int*)(smem + off),
                16, 0, 0);
        }
    }

    const int lrow = lane & 15;
    const int lk   = (lane >> 4) * 8;
    const int lkb  = (lane >> 4) * 16;

    const int rowBase = rowTileI * 128 + wid * 32;
    int r0 = rowBase + lrow;      if (r0 > n - 1) r0 = n - 1;
    int r1 = rowBase + 16 + lrow; if (r1 > n - 1) r1 = n - 1;

    const unsigned short* Ar0 = aggc + (size_t)r0 * RS;
    const unsigned short* Ar1 = aggc + (size_t)r1 * RS;
    const unsigned short* Xr0 = xc   + (size_t)r0 * RS;
    const unsigned short* Xr1 = xc   + (size_t)r1 * RS;

    // depth-2 A prefetch pipeline (slot = ks & 1)
    bf16x8 p0[2], p1[2];
    auto loadA = [&](int ks, int slot) {
        const unsigned short* P0 = (ks < 4) ? Ar0 : Xr0;
        const unsigned short* P1 = (ks < 4) ? Ar1 : Xr1;
        const int kk = (ks & 3) * 32 + lk;
        p0[slot] = *(const bf16x8*)(P0 + kk);
        p1[slot] = *(const bf16x8*)(P1 + kk);
    };
    loadA(0, 0);
    loadA(1, 1);

    // B-frag LDS addressing: byte = (cc*512 + ks*64 + lkb) ^ ((cc&7)<<4)
    int cbase[4], xmask[4];
    #pragma unroll
    for (int nf = 0; nf < 4; ++nf) {
        int cc = nf * 16 + lrow;
        cbase[nf] = (cc << 9) + lkb;
        xmask[nf] = (cc & 7) << 4;
    }

    __syncthreads();            // the ONLY barrier

    f32x4 acc[2][4];
    #pragma unroll
    for (int mf = 0; mf < 2; ++mf)
        #pragma unroll
        for (int nf = 0; nf < 4; ++nf)
            acc[mf][nf] = (f32x4){0.f, 0.f, 0.f, 0.f};

    bf16x8 b0 = *(const bf16x8*)(smem + (cbase[0] ^ xmask[0]));
    bf16x8 b1 = *(const bf16x8*)(smem + (cbase[1] ^ xmask[1]));
    bf16x8 b2 = *(const bf16x8*)(smem + (cbase[2] ^ xmask[2]));
    bf16x8 b3 = *(const bf16x8*)(smem + (cbase[3] ^ xmask[3]));

    #pragma unroll
    for (int ks = 0; ks < 8; ++ks) {
        const int slot = ks & 1;
        const bf16x8 c0 = p0[slot], c1 = p1[slot];
        const bf16x8 d0 = b0, d1 = b1, d2 = b2, d3 = b3;
        if (ks < 6) loadA(ks + 2, slot);
        if (ks < 7) {
            const int ko = (ks + 1) << 6;
            b0 = *(const bf16x8*)(smem + ((cbase[0] + ko) ^ xmask[0]));
            b1 = *(const bf16x8*)(smem + ((cbase[1] + ko) ^ xmask[1]));
            b2 = *(const bf16x8*)(smem + ((cbase[2] + ko) ^ xmask[2]));
            b3 = *(const bf16x8*)(smem + ((cbase[3] + ko) ^ xmask[3]));
        }
        acc[0][0] = __builtin_amdgcn_mfma_f32_16x16x32_bf16(c0, d0, acc[0][0], 0, 0, 0);
        acc[1][0] = __builtin_amdgcn_mfma_f32_16x16x32_bf16(c1, d0, acc[1][0], 0, 0, 0);
        acc[0][1] = __builtin_amdgcn_mfma_f32_16x16x32_bf16(c0, d1, acc[0][1], 0, 0, 0);
        acc[1][1] = __builtin_amdgcn_mfma_f32_16x16x32_bf16(c1, d1, acc[1][1], 0, 0, 0);
        acc[0][2] = __builtin_amdgcn_mfma_f32_16x16x32_bf16(c0, d2, acc[0][2], 0, 0, 0);
        acc[1][2] = __builtin_amdgcn_mfma_f32_16x16x32_bf16(c1, d2, acc[1][2], 0, 0, 0);
        acc[0][3] = __builtin_amdgcn_mfma_f32_16x16x32_bf16(c0, d3, acc[0][3], 0, 0, 0);
        acc[1][3] = __builtin_amdgcn_mfma_f32_16x16x32_bf16(c1, d3, acc[1][3], 0, 0, 0);
    }

    // epilogue: bias (+ReLU); FINAL -> fp32 out, else -> bf16 plane + fp8 shadow
    #pragma unroll
    for (int mf = 0; mf < 2; ++mf) {
        #pragma unroll
        for (int nf = 0; nf < 4; ++nf) {
            const int c = colTile + nf * 16 + lrow;
            const float bv = bias[c];
            #pragma unroll
            for (int reg = 0; reg < 4; ++reg) {
                const int r = rowBase + mf * 16 + (lane >> 4) * 4 + reg;
                if (r < n) {
                    float h = acc[mf][nf][reg] + bv;
                    if (RELU) h = fmaxf(h, 0.f);
                    if (FINAL) {
                        outF[(size_t)r * NOUT + c] = h;
                    } else {
                        outC[(size_t)r * RS + c] = f2bf(h);
                        outQ[(size_t)r * NFEAT + c] =
                            (unsigned char)(__builtin_amdgcn_cvt_pk_fp8_f32(h, h, 0, false) & 0xFF);
                    }
                }
            }
        }
    }
}

extern "C" void kernel_launch(void* const* d_in, const int* in_sizes, int n_in,
                              void* d_out, int out_size, void* d_ws, size_t ws_size,
                              hipStream_t stream) {
    const float* x   = (const float*)d_in[0];
    const int*   ei  = (const int*)d_in[1];
    const float* Wl0 = (const float*)d_in[2];
    const float* Wr0 = (const float*)d_in[3];
    const float* b0  = (const float*)d_in[4];
    const float* Wl1 = (const float*)d_in[5];
    const float* Wr1 = (const float*)d_in[6];
    const float* b1  = (const float*)d_in[7];
    const float* Wl2 = (const float*)d_in[8];
    const float* Wr2 = (const float*)d_in[9];
    const float* b2  = (const float*)d_in[10];

    const int nN = in_sizes[0] / NFEAT;       // 50000
    const int nE = in_sizes[1] / 2;           // 800000
    const int* src = ei;
    const int* dst = ei + nE;

    char* ws = (char*)d_ws;
    size_t off = 0;
    auto take = [&](size_t bytes) { char* p = ws + off; off += (bytes + 255) & ~(size_t)255; return p; };
    int*   cnt      = (int*)  take((size_t)nN * 4);
    int*   row_ptr  = (int*)  take((size_t)(nN + 1) * 4);
    int*   col_idx  = (int*)  take((size_t)nE * 4);
    float* inv_deg  = (float*)take((size_t)nN * 4);
    int*   blockSum = (int*)  take(256 * 4);
    const size_t plane  = (size_t)nN * RS * 2;            // 12.8 MB bf16
    const size_t qplane = (size_t)nN * NFEAT;             // 6.4 MB fp8
    unsigned short* aggC = (unsigned short*)take(plane);
    unsigned short* xc0  = (unsigned short*)take(plane);
    unsigned short* xc1  = (unsigned short*)take(plane);
    unsigned char*  xq0  = (unsigned char*) take(qplane);
    unsigned char*  xq1  = (unsigned char*) take(qplane);
    unsigned short* Wsz0 = (unsigned short*)take(128 * 256 * 2);
    unsigned short* Wsz1 = (unsigned short*)take(128 * 256 * 2);
    unsigned short* Wsz2 = (unsigned short*)take(64 * 256 * 2);
    (void)ws_size; (void)n_in; (void)out_size;

    const int scanBlocks = (nN + 255) / 256;
    const int sliceN = (nN + 7) / 8;

    // CSR build (XCD-sliced hist/fill; custom zero kernel)
    zero_kernel<<<scanBlocks, 256, 0, stream>>>(cnt, nN);
    hist_kernel<<<2048, 256, 0, stream>>>(dst, cnt, nE, sliceN);
    blocksum_kernel<<<scanBlocks, 256, 0, stream>>>(cnt, blockSum, nN);
    scan_write_kernel<<<scanBlocks, 256, 0, stream>>>(cnt, blockSum, row_ptr, inv_deg, nN);
    fill_kernel<<<2048, 256, 0, stream>>>(src, dst, cnt, col_idx, nE, sliceN);

    // conversions (batched)
    xconv_kernel<<<(nN * 32 + 255) / 256, 256, 0, stream>>>(x, xc0, xq0, nN);
    wconv_all_kernel<<<(81920 + 255) / 256, 256, 0, stream>>>(
        Wl0, Wr0, Wl1, Wr1, Wl2, Wr2, Wsz0, Wsz1, Wsz2);

    const int aggGrid   = (nN + 31) / 32;     // 8 lanes/node, 32 nodes/block
    const int nRowTiles = (nN + 127) / 128;
    const int gBig = nRowTiles * 2;
    const int gFin = nRowTiles;

    // layer 0: x -> h0
    agg_kernel<<<aggGrid, 256, 0, stream>>>(xq0, row_ptr, col_idx, inv_deg, aggC, nN);
    mfma_gemm<128, true, false><<<gBig, 256, 0, stream>>>(
        aggC, xc0, Wsz0, b0, nullptr, xc1, xq1, nN, nRowTiles);
    // layer 1: h0 -> h1
    agg_kernel<<<aggGrid, 256, 0, stream>>>(xq1, row_ptr, col_idx, inv_deg, aggC, nN);
    mfma_gemm<128, true, false><<<gBig, 256, 0, stream>>>(
        aggC, xc1, Wsz1, b1, nullptr, xc0, xq0, nN, nRowTiles);
    // layer 2: h1 -> out (fp32)
    agg_kernel<<<aggGrid, 256, 0, stream>>>(xq0, row_ptr, col_idx, inv_deg, aggC, nN);
    mfma_gemm<64, false, true><<<gFin, 256, 0, stream>>>(
        aggC, xc0, Wsz2, b2, (float*)d_out, nullptr, nullptr, nN, nRowTiles);
}

// Round 15
// 205.584 us; speedup vs baseline: 1.5325x; 1.0490x over previous
//
#include <hip/hip_runtime.h>

#define NFEAT 128
#define RS 128   // bf16 plane row stride in shorts

using bf16x8 = __attribute__((ext_vector_type(8))) short;
using f32x4  = __attribute__((ext_vector_type(4))) float;
using f32x2  = __attribute__((ext_vector_type(2))) float;

__device__ __forceinline__ float bf2f(unsigned short u) {
    union { unsigned int i; float f; } v; v.i = ((unsigned int)u) << 16; return v.f;
}
__device__ __forceinline__ float bfhi2f(unsigned int hi16) {
    union { unsigned int i; float f; } v; v.i = hi16; return v.f;
}
__device__ __forceinline__ unsigned short f2bf(float f) {      // RNE
    union { float f; unsigned int i; } v; v.f = f;
    unsigned int i = v.i;
    return (unsigned short)((i + 0x7FFFu + ((i >> 16) & 1u)) >> 16);
}
__device__ __forceinline__ unsigned int f4_to_fp8x4(float f0, float f1, float f2, float f3) {
    int p = __builtin_amdgcn_cvt_pk_fp8_f32(f0, f1, 0, false);
    p     = __builtin_amdgcn_cvt_pk_fp8_f32(f2, f3, p, true);
    return (unsigned int)p;
}

// ---------------- CSR build (XCD-sliced hist/fill) ----------------

__global__ void hist_kernel(const int* __restrict__ dst, int* __restrict__ cnt,
                            int nE, int sliceN) {
    const int slice = blockIdx.x & 7;
    const int lo = slice * sliceN, hi = lo + sliceN;
    const int nb = gridDim.x >> 3;
    const int bs = blockIdx.x >> 3;
    for (int i = bs * 256 + threadIdx.x; i < nE; i += nb * 256) {
        int d = dst[i];
        if (d >= lo && d < hi) atomicAdd(&cnt[d], 1);
    }
}

__global__ void fill_kernel(const int* __restrict__ src, const int* __restrict__ dst,
                            int* __restrict__ cnt, int* __restrict__ col_idx,
                            int nE, int sliceN) {
    const int slice = blockIdx.x & 7;
    const int lo = slice * sliceN, hi = lo + sliceN;
    const int nb = gridDim.x >> 3;
    const int bs = blockIdx.x >> 3;
    for (int i = bs * 256 + threadIdx.x; i < nE; i += nb * 256) {
        int d = dst[i];
        int s = src[i];
        if (d >= lo && d < hi) {
            int pos = atomicAdd(&cnt[d], 1);
            col_idx[pos] = s;
        }
    }
}

__global__ void blocksum_kernel(const int* __restrict__ cnt, int* __restrict__ blockSum, int n) {
    int i = blockIdx.x * 256 + threadIdx.x;
    int d = (i < n) ? cnt[i] : 0;
    int lane = threadIdx.x & 63, wid = threadIdx.x >> 6;
    __shared__ int ws[4];
    int v = d;
    for (int off = 32; off; off >>= 1) v += __shfl_down(v, off);
    if (lane == 0) ws[wid] = v;
    __syncthreads();
    if (threadIdx.x == 0) blockSum[blockIdx.x] = ws[0] + ws[1] + ws[2] + ws[3];
}

__global__ void scan_write_kernel(int* __restrict__ cnt, const int* __restrict__ blockSum,
                                  int* __restrict__ row_ptr, float* __restrict__ inv_deg,
                                  int n) {
    const int b = blockIdx.x, tid = threadIdx.x;
    const int lane = tid & 63, wid = tid >> 6;
    __shared__ int wsA[4];
    __shared__ int wsB[4];
    int v = (tid < b) ? blockSum[tid] : 0;
    for (int off = 32; off; off >>= 1) v += __shfl_down(v, off);
    if (lane == 0) wsA[wid] = v;
    int i = b * 256 + tid;
    int d = (i < n) ? cnt[i] : 0;
    int s = d;
    for (int off = 1; off < 64; off <<= 1) {
        int t = __shfl_up(s, off);
        if (lane >= off) s += t;
    }
    if (lane == 63) wsB[wid] = s;
    __syncthreads();
    int blockOff = wsA[0] + wsA[1] + wsA[2] + wsA[3];
    int wOff = 0;
    for (int w = 0; w < wid; ++w) wOff += wsB[w];
    int excl = blockOff + wOff + s - d;
    if (i < n) {
        row_ptr[i] = excl;
        cnt[i]     = excl;
        inv_deg[i] = 1.0f / (float)(d > 1 ? d : 1);
    }
    if (i == n) row_ptr[n] = excl;
}

// ---------------- fused prep: xconv + all wconv + zero(cnt), ONE launch ----------------

__global__ void prep_kernel(const float* __restrict__ x,
                            unsigned short* __restrict__ xc, unsigned char* __restrict__ xq,
                            const float* __restrict__ Wl0, const float* __restrict__ Wr0,
                            const float* __restrict__ Wl1, const float* __restrict__ Wr1,
                            const float* __restrict__ Wl2, const float* __restrict__ Wr2,
                            unsigned short* __restrict__ Wsz0,
                            unsigned short* __restrict__ Wsz1,
                            unsigned short* __restrict__ Wsz2,
                            int* __restrict__ cnt, int n) {
    int idx = blockIdx.x * 256 + threadIdx.x;
    const int R0 = n * 32;
    if (idx < R0) {
        // xconv: fp32 -> bf16 plane + fp8 shadow, 4 features/thread
        int node = idx >> 5, fb = (idx & 31) * 4;
        float4 v = *(const float4*)(x + (size_t)node * NFEAT + fb);
        uint2 hw;
        hw.x = (unsigned int)f2bf(v.x) | ((unsigned int)f2bf(v.y) << 16);
        hw.y = (unsigned int)f2bf(v.z) | ((unsigned int)f2bf(v.w) << 16);
        *(uint2*)(xc + (size_t)node * RS + fb) = hw;
        *(unsigned int*)(xq + (size_t)node * NFEAT + fb) = f4_to_fp8x4(v.x, v.y, v.z, v.w);
        return;
    }
    idx -= R0;
    if (idx < 81920) {
        // wconv: transposed K-major [nout][256], pre-swizzled (k ^ ((c&7)<<3))
        const float* Wl; const float* Wr; unsigned short* Wsz; int nout; int li;
        if (idx < 32768)      { Wl = Wl0; Wr = Wr0; Wsz = Wsz0; nout = 128; li = idx; }
        else if (idx < 65536) { Wl = Wl1; Wr = Wr1; Wsz = Wsz1; nout = 128; li = idx - 32768; }
        else                  { Wl = Wl2; Wr = Wr2; Wsz = Wsz2; nout = 64;  li = idx - 65536; }
        int c = li >> 8, k = li & 255;
        float f = (k < 128) ? Wl[k * nout + c] : Wr[(k - 128) * nout + c];
        Wsz[c * 256 + (k ^ ((c & 7) << 3))] = f2bf(f);
        return;
    }
    idx -= 81920;
    if (idx < n) cnt[idx] = 0;
}

// ---------------- fused layer: gather-mean (fp8) -> LDS -> MFMA GEMM ----------------
// Round-15: agg fused into the GEMM as a per-block prologue (numerics identical
// to round-14: mean in fp32 -> bf16 -> MFMA). Removes the aggC global buffer
// (38 MB/layer of traffic) and 4 dispatches. Block = 512 threads (8 waves),
// 64 rows, NOUT cols via HALVES sequential 64-col W stages from one 32KB
// W-LDS buffer. A-tile (64x128 bf16, 16KB) XOR-swizzled chunk^=(row&7) so
// gather ds_writes and frag ds_reads stay <=2-way. x-side (ks 4-7) prefetched
// to regs BEFORE the gather (drains underneath it). LDS 48KB -> 2-3 blocks/CU.

template<int NOUT, bool RELU, bool FINAL>
__global__ __launch_bounds__(512, 4) void layer_kernel(
    const unsigned char* __restrict__ xq, const unsigned short* __restrict__ xc,
    const int* __restrict__ row_ptr, const int* __restrict__ col_idx,
    const float* __restrict__ inv_deg,
    const unsigned short* __restrict__ Wsz, const float* __restrict__ bias,
    float* __restrict__ outF, unsigned short* __restrict__ outC,
    unsigned char* __restrict__ outQ, int n)
{
    constexpr int HALVES = NOUT / 64;
    constexpr int AOFF = 32768;
    __shared__ char smem[32768 + 16384];   // W half (32KB) | A tile (16KB)
    const int tid  = threadIdx.x;
    const int lane = tid & 63;
    const int wid  = tid >> 6;             // 0..7
    const int rowBase = blockIdx.x * 64;

    // ---- stage W half 0 via global_load_lds (lane-linear) ----
    {
        const char* wsrc = (const char*)Wsz;
        #pragma unroll
        for (int i = 0; i < 4; ++i) {
            const int off = (i * 512 + tid) * 16;
            __builtin_amdgcn_global_load_lds(
                (const __attribute__((address_space(1))) unsigned int*)(wsrc + off),
                (__attribute__((address_space(3))) unsigned int*)(smem + off),
                16, 0, 0);
        }
    }

    // ---- x-side prefetch (ks 4..7), issued BEFORE gather so HBM latency hides ----
    const int lrow = lane & 15;
    const int lk   = (lane >> 4) * 8;
    const int rg   = wid >> 1;             // row group (16 rows each)
    const int cg   = wid & 1;              // col group (32 cols each)
    int r0 = rowBase + rg * 16 + lrow; if (r0 > n - 1) r0 = n - 1;
    const unsigned short* Xr = xc + (size_t)r0 * RS;
    bf16x8 xr[4];
    #pragma unroll
    for (int ks = 0; ks < 4; ++ks) xr[ks] = *(const bf16x8*)(Xr + ks * 32 + lk);
    __builtin_amdgcn_sched_barrier(0);

    // ---- gather: 64 nodes, 8 lanes/node, fp8 rows, fp32 accumulate ----
    {
        const int l    = tid & 7;
        const int nd   = tid >> 3;         // 0..63
        const int node = rowBase + nd;
        if (node < n) {
            int beg = row_ptr[node], end = row_ptr[node + 1];
            float a[2][16];
            #pragma unroll
            for (int u = 0; u < 2; ++u)
                #pragma unroll
                for (int j = 0; j < 16; ++j) a[u][j] = 0.f;
            auto acc16 = [&](float* A, uint4 v) {
                f32x2 d;
                d = __builtin_amdgcn_cvt_pk_f32_fp8(v.x, false); A[0]  += d[0]; A[1]  += d[1];
                d = __builtin_amdgcn_cvt_pk_f32_fp8(v.x, true);  A[2]  += d[0]; A[3]  += d[1];
                d = __builtin_amdgcn_cvt_pk_f32_fp8(v.y, false); A[4]  += d[0]; A[5]  += d[1];
                d = __builtin_amdgcn_cvt_pk_f32_fp8(v.y, true);  A[6]  += d[0]; A[7]  += d[1];
                d = __builtin_amdgcn_cvt_pk_f32_fp8(v.z, false); A[8]  += d[0]; A[9]  += d[1];
                d = __builtin_amdgcn_cvt_pk_f32_fp8(v.z, true);  A[10] += d[0]; A[11] += d[1];
                d = __builtin_amdgcn_cvt_pk_f32_fp8(v.w, false); A[12] += d[0]; A[13] += d[1];
                d = __builtin_amdgcn_cvt_pk_f32_fp8(v.w, true);  A[14] += d[0]; A[15] += d[1];
            };
            int e = beg;
            for (; e + 8 <= end; e += 8) {
                uint4 v[8];
                #pragma unroll
                for (int u = 0; u < 8; ++u) {
                    int s = col_idx[e + u];
                    v[u] = *(const uint4*)(xq + (size_t)s * NFEAT + l * 16);
                }
                #pragma unroll
                for (int u = 0; u < 8; ++u) acc16(a[u & 1], v[u]);
            }
            for (; e < end; ++e) {
                int s = col_idx[e];
                uint4 v = *(const uint4*)(xq + (size_t)s * NFEAT + l * 16);
                acc16(a[0], v);
            }
            float sc = inv_deg[node];
            unsigned short hs[16];
            #pragma unroll
            for (int j = 0; j < 16; ++j)
                hs[j] = f2bf((a[0][j] + a[1][j]) * sc);
            uint4 h0, h1;
            h0.x = (unsigned int)hs[0]  | ((unsigned int)hs[1]  << 16);
            h0.y = (unsigned int)hs[2]  | ((unsigned int)hs[3]  << 16);
            h0.z = (unsigned int)hs[4]  | ((unsigned int)hs[5]  << 16);
            h0.w = (unsigned int)hs[6]  | ((unsigned int)hs[7]  << 16);
            h1.x = (unsigned int)hs[8]  | ((unsigned int)hs[9]  << 16);
            h1.y = (unsigned int)hs[10] | ((unsigned int)hs[11] << 16);
            h1.z = (unsigned int)hs[12] | ((unsigned int)hs[13] << 16);
            h1.w = (unsigned int)hs[14] | ((unsigned int)hs[15] << 16);
            // A-LDS write, chunk-swizzled: chunk c holds feats [8c,8c+8), c ^= nd&7
            const int s_ = nd & 7;
            char* arow = smem + AOFF + nd * 256;
            *(uint4*)(arow + (((2 * l)     ^ s_) << 4)) = h0;
            *(uint4*)(arow + (((2 * l + 1) ^ s_) << 4)) = h1;
        }
    }

    __syncthreads();                       // W half0 + A tile + xr all resident

    // B-frag addressing within current W half: cc in [0,64)
    const int cc0 = cg * 32 + lrow;
    const int cc1 = cg * 32 + 16 + lrow;
    const int cb0 = (cc0 << 9) + ((lane >> 4) * 16), xm0 = (cc0 & 7) << 4;
    const int cb1 = (cc1 << 9) + ((lane >> 4) * 16), xm1 = (cc1 & 7) << 4;
    // A-frag addressing
    const int ar    = rg * 16 + lrow;
    const int abase = AOFF + ar * 256;
    const int as    = ar & 7;

    #pragma unroll
    for (int h = 0; h < HALVES; ++h) {
        if (h > 0) {
            __syncthreads();               // half-0 reads done before overwrite
            const char* wsrc = (const char*)(Wsz + (size_t)h * 64 * 256);
            #pragma unroll
            for (int i = 0; i < 4; ++i) {
                const int off = (i * 512 + tid) * 16;
                __builtin_amdgcn_global_load_lds(
                    (const __attribute__((address_space(1))) unsigned int*)(wsrc + off),
                    (__attribute__((address_space(3))) unsigned int*)(smem + off),
                    16, 0, 0);
            }
            __syncthreads();               // W half1 resident
        }

        f32x4 acc0 = (f32x4){0.f, 0.f, 0.f, 0.f};
        f32x4 acc1 = (f32x4){0.f, 0.f, 0.f, 0.f};

        #pragma unroll
        for (int ks = 0; ks < 8; ++ks) {
            bf16x8 a;
            if (ks < 4)
                a = *(const bf16x8*)(smem + abase + (((ks * 4 + (lane >> 4)) ^ as) << 4));
            else
                a = xr[ks - 4];
            bf16x8 b0 = *(const bf16x8*)(smem + ((cb0 + (ks << 6)) ^ xm0));
            bf16x8 b1 = *(const bf16x8*)(smem + ((cb1 + (ks << 6)) ^ xm1));
            acc0 = __builtin_amdgcn_mfma_f32_16x16x32_bf16(a, b0, acc0, 0, 0, 0);
            acc1 = __builtin_amdgcn_mfma_f32_16x16x32_bf16(a, b1, acc1, 0, 0, 0);
        }

        // epilogue for this half
        #pragma unroll
        for (int nf = 0; nf < 2; ++nf) {
            const f32x4 av = nf ? acc1 : acc0;
            const int c = h * 64 + cg * 32 + nf * 16 + lrow;
            const float bv = bias[c];
            #pragma unroll
            for (int reg = 0; reg < 4; ++reg) {
                const int r = rowBase + rg * 16 + (lane >> 4) * 4 + reg;
                if (r < n) {
                    float hv = av[reg] + bv;
                    if (RELU) hv = fmaxf(hv, 0.f);
                    if (FINAL) {
                        outF[(size_t)r * NOUT + c] = hv;
                    } else {
                        outC[(size_t)r * RS + c] = f2bf(hv);
                        outQ[(size_t)r * NFEAT + c] =
                            (unsigned char)(__builtin_amdgcn_cvt_pk_fp8_f32(hv, hv, 0, false) & 0xFF);
                    }
                }
            }
        }
    }
}

extern "C" void kernel_launch(void* const* d_in, const int* in_sizes, int n_in,
                              void* d_out, int out_size, void* d_ws, size_t ws_size,
                              hipStream_t stream) {
    const float* x   = (const float*)d_in[0];
    const int*   ei  = (const int*)d_in[1];
    const float* Wl0 = (const float*)d_in[2];
    const float* Wr0 = (const float*)d_in[3];
    const float* b0  = (const float*)d_in[4];
    const float* Wl1 = (const float*)d_in[5];
    const float* Wr1 = (const float*)d_in[6];
    const float* b1  = (const float*)d_in[7];
    const float* Wl2 = (const float*)d_in[8];
    const float* Wr2 = (const float*)d_in[9];
    const float* b2  = (const float*)d_in[10];

    const int nN = in_sizes[0] / NFEAT;       // 50000
    const int nE = in_sizes[1] / 2;           // 800000
    const int* src = ei;
    const int* dst = ei + nE;

    char* ws = (char*)d_ws;
    size_t off = 0;
    auto take = [&](size_t bytes) { char* p = ws + off; off += (bytes + 255) & ~(size_t)255; return p; };
    int*   cnt      = (int*)  take((size_t)nN * 4);
    int*   row_ptr  = (int*)  take((size_t)(nN + 1) * 4);
    int*   col_idx  = (int*)  take((size_t)nE * 4);
    float* inv_deg  = (float*)take((size_t)nN * 4);
    int*   blockSum = (int*)  take(256 * 4);
    const size_t plane  = (size_t)nN * RS * 2;            // 12.8 MB bf16
    const size_t qplane = (size_t)nN * NFEAT;             // 6.4 MB fp8
    unsigned short* xc0  = (unsigned short*)take(plane);
    unsigned short* xc1  = (unsigned short*)take(plane);
    unsigned char*  xq0  = (unsigned char*) take(qplane);
    unsigned char*  xq1  = (unsigned char*) take(qplane);
    unsigned short* Wsz0 = (unsigned short*)take(128 * 256 * 2);
    unsigned short* Wsz1 = (unsigned short*)take(128 * 256 * 2);
    unsigned short* Wsz2 = (unsigned short*)take(64 * 256 * 2);
    (void)ws_size; (void)n_in; (void)out_size;

    const int scanBlocks = (nN + 255) / 256;
    const int sliceN = (nN + 7) / 8;

    // prep: xconv + wconv x3 + zero(cnt) in one launch
    const int prepTotal = nN * 32 + 81920 + nN;
    prep_kernel<<<(prepTotal + 255) / 256, 256, 0, stream>>>(
        x, xc0, xq0, Wl0, Wr0, Wl1, Wr1, Wl2, Wr2, Wsz0, Wsz1, Wsz2, cnt, nN);

    // CSR build (XCD-sliced hist/fill)
    hist_kernel<<<2048, 256, 0, stream>>>(dst, cnt, nE, sliceN);
    blocksum_kernel<<<scanBlocks, 256, 0, stream>>>(cnt, blockSum, nN);
    scan_write_kernel<<<scanBlocks, 256, 0, stream>>>(cnt, blockSum, row_ptr, inv_deg, nN);
    fill_kernel<<<2048, 256, 0, stream>>>(src, dst, cnt, col_idx, nE, sliceN);

    const int layerGrid = (nN + 63) / 64;     // 782

    // layer 0: x -> h0
    layer_kernel<128, true, false><<<layerGrid, 512, 0, stream>>>(
        xq0, xc0, row_ptr, col_idx, inv_deg, Wsz0, b0, nullptr, xc1, xq1, nN);
    // layer 1: h0 -> h1
    layer_kernel<128, true, false><<<layerGrid, 512, 0, stream>>>(
        xq1, xc1, row_ptr, col_idx, inv_deg, Wsz1, b1, nullptr, xc0, xq0, nN);
    // layer 2: h1 -> out (fp32)
    layer_kernel<64, false, true><<<layerGrid, 512, 0, stream>>>(
        xq0, xc0, row_ptr, col_idx, inv_deg, Wsz2, b2, (float*)d_out, nullptr, nullptr, nN);
}